// Round 1
// baseline (2797.212 us; speedup 1.0000x reference)
//
#include <hip/hip_runtime.h>
#include <cstdint>
#include <cstddef>

#define NEG_INF -10000.0f

constexpr int BSZ  = 128;
constexpr int SEQ  = 64;     // L
constexpr int DIM  = 512;    // D
constexpr int HEADS = 8;
constexpr int NLAYER = 2;
constexpr int NCOL = BSZ * (SEQ + 1);   // 8320
constexpr int NROW = BSZ * SEQ;         // 8192

// ---------------------------------------------------------------- helpers
__device__ __forceinline__ float gelu_f(float v) {
    // tanh approximation (jax.nn.gelu default approximate=True)
    float u = 0.7978845608028654f * (v + 0.044715f * v * v * v);
    return 0.5f * v * (1.0f + tanhf(u));
}

__device__ __forceinline__ float block_sum_256(float v, float* sh) {
    #pragma unroll
    for (int off = 32; off > 0; off >>= 1) v += __shfl_down(v, off, 64);
    const int lane = threadIdx.x & 63, w = threadIdx.x >> 6;
    __syncthreads();
    if (lane == 0) sh[w] = v;
    __syncthreads();
    return sh[0] + sh[1] + sh[2] + sh[3];
}

// ---------------------------------------------------------------- gather
__global__ __launch_bounds__(128) void gather_kernel(
    const int* __restrict__ ids, const float* __restrict__ table,
    const float* __restrict__ pop, float* __restrict__ se, float* __restrict__ debias) {
    const int k = blockIdx.x;
    const int id = ids[k];
    const float4* src = reinterpret_cast<const float4*>(table + (size_t)id * DIM);
    float4* dst = reinterpret_cast<float4*>(se + (size_t)k * DIM);
    dst[threadIdx.x] = src[threadIdx.x];
    if (threadIdx.x == 0) debias[k] = logf(pop[id]);
}

// ---------------------------------------------------------------- masks
// colmask[i][k] = pad_col(k) || member(i,k);  padcol[k] = pad_col(k)
__global__ __launch_bounds__(256) void mask_kernel(
    const int* __restrict__ ids, const float* __restrict__ log_mask,
    uint8_t* __restrict__ colmask, uint8_t* __restrict__ padcol) {
    const int bi = blockIdx.x;
    __shared__ int sid[65];
    if (threadIdx.x < 65) sid[threadIdx.x] = ids[bi * 65 + threadIdx.x];
    __syncthreads();
    for (int k = threadIdx.x; k < NCOL; k += 256) {
        const int id = ids[k];
        bool mem = false;
        #pragma unroll
        for (int j = 0; j < 65; j++) mem |= (sid[j] == id);
        const int i2 = k / 65, jj = k - i2 * 65;
        const bool pc = (jj < 64) && (log_mask[i2 * 64 + jj] == 0.0f);
        colmask[(size_t)bi * NCOL + k] = (mem || pc) ? 1 : 0;
        if (bi == 0) padcol[k] = pc ? 1 : 0;
    }
}

// ---------------------------------------------------------------- LN kernels
__global__ __launch_bounds__(256) void add_pos_ln_kernel(
    const float* __restrict__ se, const float* __restrict__ pos, float* __restrict__ x) {
    __shared__ float sh[4];
    const int r = blockIdx.x, b = r >> 6, s = r & 63, t = threadIdx.x;
    const float* src = se + ((size_t)b * 65 + s) * DIM;
    const float* pp  = pos + (size_t)s * DIM;
    float v0 = src[t]       + pp[t];
    float v1 = src[t + 256] + pp[t + 256];
    float sum = block_sum_256(v0 + v1, sh);
    float sq  = block_sum_256(v0 * v0 + v1 * v1, sh);
    float mean = sum * (1.0f / 512.0f);
    float var  = sq  * (1.0f / 512.0f) - mean * mean;
    float rs = rsqrtf(var + 1e-5f);
    float* dst = x + (size_t)r * DIM;
    dst[t]       = (v0 - mean) * rs;
    dst[t + 256] = (v1 - mean) * rs;
}

__global__ __launch_bounds__(256) void resid_ln_kernel(
    float* __restrict__ x, const float* __restrict__ y) {
    __shared__ float sh[4];
    const int r = blockIdx.x, t = threadIdx.x;
    float* xr = x + (size_t)r * DIM;
    const float* yr = y + (size_t)r * DIM;
    float v0 = xr[t]       + yr[t];
    float v1 = xr[t + 256] + yr[t + 256];
    float sum = block_sum_256(v0 + v1, sh);
    float sq  = block_sum_256(v0 * v0 + v1 * v1, sh);
    float mean = sum * (1.0f / 512.0f);
    float var  = sq  * (1.0f / 512.0f) - mean * mean;
    float rs = rsqrtf(var + 1e-5f);
    xr[t]       = (v0 - mean) * rs;
    xr[t + 256] = (v1 - mean) * rs;
}

// ---------------------------------------------------------------- generic fp32 GEMM
// C[M,N] = A[M,K] @ B[K,N]; 64x64 block tile, 256 threads, 4x4 micro, K-tile 16.
__global__ __launch_bounds__(256) void gemm64_kernel(
    const float* __restrict__ A, const float* __restrict__ B, float* __restrict__ C,
    int N, int K, int gelu_flag) {
    __shared__ float As[16][68];
    __shared__ float Bs[16][68];
    const int tid = threadIdx.x;
    const int tx = tid & 15, ty = tid >> 4;
    const int row0 = blockIdx.y * 64, col0 = blockIdx.x * 64;
    const int am = tid >> 2, akq = tid & 3;   // A: rows x k-quads
    const int bk = tid >> 4, bn4 = tid & 15;  // B: k-rows x col-quads
    float acc[4][4] = {};
    for (int k0 = 0; k0 < K; k0 += 16) {
        float4 av = *reinterpret_cast<const float4*>(&A[(size_t)(row0 + am) * K + k0 + akq * 4]);
        float4 bv = *reinterpret_cast<const float4*>(&B[(size_t)(k0 + bk) * N + col0 + bn4 * 4]);
        As[akq * 4 + 0][am] = av.x;
        As[akq * 4 + 1][am] = av.y;
        As[akq * 4 + 2][am] = av.z;
        As[akq * 4 + 3][am] = av.w;
        *reinterpret_cast<float4*>(&Bs[bk][bn4 * 4]) = bv;
        __syncthreads();
        #pragma unroll
        for (int kk = 0; kk < 16; kk++) {
            float4 a = *reinterpret_cast<const float4*>(&As[kk][ty * 4]);
            float4 b = *reinterpret_cast<const float4*>(&Bs[kk][tx * 4]);
            const float aa[4] = {a.x, a.y, a.z, a.w};
            const float bb[4] = {b.x, b.y, b.z, b.w};
            #pragma unroll
            for (int i = 0; i < 4; i++)
                #pragma unroll
                for (int j = 0; j < 4; j++) acc[i][j] += aa[i] * bb[j];
        }
        __syncthreads();
    }
    #pragma unroll
    for (int i = 0; i < 4; i++) {
        float4 v;
        float* vp = reinterpret_cast<float*>(&v);
        #pragma unroll
        for (int j = 0; j < 4; j++) {
            float u = acc[i][j];
            if (gelu_flag) u = gelu_f(u);
            vp[j] = u;
        }
        *reinterpret_cast<float4*>(&C[(size_t)(row0 + ty * 4 + i) * N + col0 + tx * 4]) = v;
    }
}

// ---------------------------------------------------------------- attention (per b,h)
__global__ __launch_bounds__(256) void attn_kernel(
    const float* __restrict__ qkv, const float* __restrict__ log_mask,
    float* __restrict__ obuf) {
    const int b = blockIdx.x >> 3, h = blockIdx.x & 7;
    __shared__ float QV[64][64];   // Q, then reused for V
    __shared__ float Ks[64][65];   // Ks[d][k] (transposed, padded)
    __shared__ float P[64][64];
    const int tid = threadIdx.x;
    const int w = tid >> 6, lane = tid & 63;
    #pragma unroll
    for (int p = 0; p < 16; p++) {
        int s = p * 4 + w;
        size_t base = (size_t)(b * 64 + s) * 1536 + h * 64 + lane;
        QV[s][lane] = qkv[base];
        Ks[lane][s] = qkv[base + 512];
    }
    __syncthreads();
    #pragma unroll
    for (int p = 0; p < 16; p++) {
        int q = p * 4 + w;
        float acc = 0.f;
        #pragma unroll
        for (int d = 0; d < 64; d++) acc += QV[q][d] * Ks[d][lane];
        bool ok = (lane <= q) && (log_mask[b * 64 + lane] != 0.0f);
        P[q][lane] = acc * 0.125f + (ok ? 0.0f : NEG_INF);
    }
    __syncthreads();
    // load V into QV (Q no longer needed); softmax rows (wave-private rows, no race)
    #pragma unroll
    for (int p = 0; p < 16; p++) {
        int s = p * 4 + w;
        QV[s][lane] = qkv[(size_t)(b * 64 + s) * 1536 + 1024 + h * 64 + lane];
    }
    #pragma unroll
    for (int p = 0; p < 16; p++) {
        int q = p * 4 + w;
        float v = P[q][lane];
        float m = v;
        #pragma unroll
        for (int off = 32; off > 0; off >>= 1) m = fmaxf(m, __shfl_xor(m, off, 64));
        float e = expf(v - m);
        float s = e;
        #pragma unroll
        for (int off = 32; off > 0; off >>= 1) s += __shfl_xor(s, off, 64);
        P[q][lane] = e / s;
    }
    __syncthreads();
    #pragma unroll
    for (int p = 0; p < 16; p++) {
        int q = p * 4 + w;
        float acc = 0.f;
        #pragma unroll
        for (int k = 0; k < 64; k++) acc += P[q][k] * QV[k][lane];
        obuf[(size_t)(b * 64 + q) * 512 + h * 64 + lane] = acc;
    }
}

// ---------------------------------------------------------------- fused logits strip
// grid = 128 batches x 65 strips of 128 cols. Per block: 64x128x512 GEMM tile,
// mask + debias, per-row online-softmax partials (m, sumexp), label capture.
__global__ __launch_bounds__(256) void logits_strip_kernel(
    const float* __restrict__ prec, const float* __restrict__ se,
    const float* __restrict__ debias, const uint8_t* __restrict__ colmask,
    const uint8_t* __restrict__ padcol,
    float* __restrict__ partials, float* __restrict__ label_logit) {
    const int bi = blockIdx.x / 65;
    const int st = blockIdx.x - bi * 65;
    const int col0 = st * 128;
    __shared__ float As[16][68];
    __shared__ float Bs[16][132];
    const int tid = threadIdx.x;
    const int tx = tid & 15, ty = tid >> 4;
    const float* A = prec + (size_t)bi * 64 * DIM;
    const int am = tid >> 2, akq = tid & 3;   // A: 64 rows x 4 k-quads
    const int bc = tid >> 1, bkq = tid & 1;   // B: 128 cols x 2 k-octs
    float acc[4][8] = {};
    for (int k0 = 0; k0 < DIM; k0 += 16) {
        float4 av  = *reinterpret_cast<const float4*>(&A[(size_t)am * DIM + k0 + akq * 4]);
        const float* brow = se + (size_t)(col0 + bc) * DIM + k0 + bkq * 8;
        float4 bv0 = *reinterpret_cast<const float4*>(brow);
        float4 bv1 = *reinterpret_cast<const float4*>(brow + 4);
        As[akq * 4 + 0][am] = av.x;
        As[akq * 4 + 1][am] = av.y;
        As[akq * 4 + 2][am] = av.z;
        As[akq * 4 + 3][am] = av.w;
        Bs[bkq * 8 + 0][bc] = bv0.x;
        Bs[bkq * 8 + 1][bc] = bv0.y;
        Bs[bkq * 8 + 2][bc] = bv0.z;
        Bs[bkq * 8 + 3][bc] = bv0.w;
        Bs[bkq * 8 + 4][bc] = bv1.x;
        Bs[bkq * 8 + 5][bc] = bv1.y;
        Bs[bkq * 8 + 6][bc] = bv1.z;
        Bs[bkq * 8 + 7][bc] = bv1.w;
        __syncthreads();
        #pragma unroll
        for (int kk = 0; kk < 16; kk++) {
            float4 a  = *reinterpret_cast<const float4*>(&As[kk][ty * 4]);
            float4 b0 = *reinterpret_cast<const float4*>(&Bs[kk][tx * 8]);
            float4 b1 = *reinterpret_cast<const float4*>(&Bs[kk][tx * 8 + 4]);
            const float aa[4] = {a.x, a.y, a.z, a.w};
            const float bb[8] = {b0.x, b0.y, b0.z, b0.w, b1.x, b1.y, b1.z, b1.w};
            #pragma unroll
            for (int i = 0; i < 4; i++)
                #pragma unroll
                for (int j = 0; j < 8; j++) acc[i][j] += aa[i] * bb[j];
        }
        __syncthreads();
    }
    const uint8_t* cm = colmask + (size_t)bi * NCOL;
    #pragma unroll
    for (int i = 0; i < 4; i++) {
        const int q = ty * 4 + i;
        const int label = bi * 65 + q + 1;
        const int row = bi * 64 + q;
        float vals[8];
        #pragma unroll
        for (int j = 0; j < 8; j++) {
            const int k = col0 + tx * 8 + j;
            float v = acc[i][j] - debias[k];
            const bool is_lab = (k == label);
            const bool masked = is_lab ? (padcol[k] != 0) : (cm[k] != 0);
            if (masked) v = NEG_INF;
            vals[j] = v;
            if (is_lab) label_logit[row] = v;
        }
        float m = vals[0];
        #pragma unroll
        for (int j = 1; j < 8; j++) m = fmaxf(m, vals[j]);
        #pragma unroll
        for (int off = 1; off < 16; off <<= 1) m = fmaxf(m, __shfl_xor(m, off, 64));
        float s = 0.f;
        #pragma unroll
        for (int j = 0; j < 8; j++) s += expf(vals[j] - m);
        #pragma unroll
        for (int off = 1; off < 16; off <<= 1) s += __shfl_xor(s, off, 64);
        if (tx == 0) {
            partials[((size_t)row * 65 + st) * 2 + 0] = m;
            partials[((size_t)row * 65 + st) * 2 + 1] = s;
        }
    }
}

// ---------------------------------------------------------------- combine + reduce
__global__ __launch_bounds__(256) void combine_kernel(
    const float* __restrict__ partials, const float* __restrict__ label_logit,
    const float* __restrict__ log_mask, float* __restrict__ bsums) {
    const int row = blockIdx.x * 256 + threadIdx.x;
    const float* p = partials + (size_t)row * 130;
    float M = -3.4e38f;
    for (int t = 0; t < 65; t++) M = fmaxf(M, p[2 * t]);
    float Ls = 0.f;
    for (int t = 0; t < 65; t++) Ls += p[2 * t + 1] * expf(p[2 * t] - M);
    const float lse = M + logf(Ls);
    const float valid = (log_mask[row] != 0.0f) ? 1.0f : 0.0f;
    float a = (lse - label_logit[row]) * valid;
    float c = valid;
    __shared__ float sa[4], sc[4];
    #pragma unroll
    for (int off = 32; off > 0; off >>= 1) {
        a += __shfl_down(a, off, 64);
        c += __shfl_down(c, off, 64);
    }
    const int lane = threadIdx.x & 63, w = threadIdx.x >> 6;
    if (lane == 0) { sa[w] = a; sc[w] = c; }
    __syncthreads();
    if (threadIdx.x == 0) {
        bsums[blockIdx.x * 2 + 0] = sa[0] + sa[1] + sa[2] + sa[3];
        bsums[blockIdx.x * 2 + 1] = sc[0] + sc[1] + sc[2] + sc[3];
    }
}

__global__ __launch_bounds__(64) void finalize_kernel(
    const float* __restrict__ bsums, float* __restrict__ out) {
    const int t = threadIdx.x;
    float a = 0.f, c = 0.f;
    if (t < 32) { a = bsums[2 * t]; c = bsums[2 * t + 1]; }
    #pragma unroll
    for (int off = 32; off > 0; off >>= 1) {
        a += __shfl_down(a, off, 64);
        c += __shfl_down(c, off, 64);
    }
    if (t == 0) out[0] = a / c;
}

// ---------------------------------------------------------------- launch
extern "C" void kernel_launch(void* const* d_in, const int* in_sizes, int n_in,
                              void* d_out, int out_size, void* d_ws, size_t ws_size,
                              hipStream_t stream) {
    const int*   ids    = (const int*)d_in[0];
    const float* lm     = (const float*)d_in[1];
    const float* emb    = (const float*)d_in[2];
    const float* pos    = (const float*)d_in[3];
    const float* qkv_w  = (const float*)d_in[4];
    const float* out_w  = (const float*)d_in[5];
    const float* ffn1_w = (const float*)d_in[6];
    const float* ffn2_w = (const float*)d_in[7];
    const float* pop    = (const float*)d_in[8];
    float* out = (float*)d_out;

    char* p = (char*)d_ws;
    auto alloc = [&](size_t bytes) {
        char* r = p;
        p += (bytes + 255) & ~(size_t)255;
        return r;
    };
    float*   se       = (float*)alloc((size_t)NCOL * DIM * 4);       // 17.0 MB
    float*   debias   = (float*)alloc((size_t)NCOL * 4);
    uint8_t* padcol   = (uint8_t*)alloc(NCOL);
    uint8_t* colmask  = (uint8_t*)alloc((size_t)BSZ * NCOL);         // 1.06 MB
    float*   x        = (float*)alloc((size_t)NROW * DIM * 4);       // 16.8 MB
    float*   obuf     = (float*)alloc((size_t)NROW * DIM * 4);       // 16.8 MB
    float*   big      = (float*)alloc((size_t)NROW * 2048 * 4);      // 67.1 MB (qkv / proj / h)
    float*   partials = (float*)alloc((size_t)NROW * 65 * 2 * 4);    // 4.26 MB
    float*   lab      = (float*)alloc((size_t)NROW * 4);
    float*   bsums    = (float*)alloc(64 * 4);

    gather_kernel<<<NCOL, 128, 0, stream>>>(ids, emb, pop, se, debias);
    mask_kernel<<<BSZ, 256, 0, stream>>>(ids, lm, colmask, padcol);
    add_pos_ln_kernel<<<NROW, 256, 0, stream>>>(se, pos, x);

    for (int l = 0; l < NLAYER; l++) {
        // qkv = x @ qkv_w[l]   [8192,512]@[512,1536] -> big
        gemm64_kernel<<<dim3(1536 / 64, NROW / 64), 256, 0, stream>>>(
            x, qkv_w + (size_t)l * 512 * 1536, big, 1536, 512, 0);
        // attention -> obuf
        attn_kernel<<<BSZ * HEADS, 256, 0, stream>>>(big, lm, obuf);
        // proj = obuf @ out_w[l] -> big (qkv consumed)
        gemm64_kernel<<<dim3(512 / 64, NROW / 64), 256, 0, stream>>>(
            obuf, out_w + (size_t)l * 512 * 512, big, 512, 512, 0);
        // x = LN(x + proj)
        resid_ln_kernel<<<NROW, 256, 0, stream>>>(x, big);
        // h = gelu(x @ ffn1_w[l]) -> big
        gemm64_kernel<<<dim3(2048 / 64, NROW / 64), 256, 0, stream>>>(
            x, ffn1_w + (size_t)l * 512 * 2048, big, 2048, 512, 1);
        // f2 = h @ ffn2_w[l] -> obuf
        gemm64_kernel<<<dim3(512 / 64, NROW / 64), 256, 0, stream>>>(
            big, ffn2_w + (size_t)l * 2048 * 512, obuf, 512, 2048, 0);
        // x = LN(x + f2)
        resid_ln_kernel<<<NROW, 256, 0, stream>>>(x, obuf);
    }

    logits_strip_kernel<<<BSZ * 65, 256, 0, stream>>>(
        x, se, debias, colmask, padcol, partials, lab);
    combine_kernel<<<NROW / 256, 256, 0, stream>>>(partials, lab, lm, bsums);
    finalize_kernel<<<1, 64, 0, stream>>>(bsums, out);
}

// Round 2
// 919.604 us; speedup vs baseline: 3.0418x; 3.0418x over previous
//
#include <hip/hip_runtime.h>
#include <hip/hip_bf16.h>
#include <cstdint>
#include <cstddef>

#define NEG_INF -10000.0f

constexpr int BSZ  = 128;
constexpr int SEQ  = 64;     // L
constexpr int DIM  = 512;    // D
constexpr int HEADS = 8;
constexpr int NLAYER = 2;
constexpr int NCOL = BSZ * (SEQ + 1);   // 8320
constexpr int NROW = BSZ * SEQ;         // 8192

typedef __attribute__((ext_vector_type(8))) short bf16x8;   // 8 bf16 in 4 VGPRs
typedef __attribute__((ext_vector_type(4))) float f32x4;

// async global->LDS, 16B per lane, dest = ldsbase + lane*16
__device__ __forceinline__ void async_copy16(const void* g, void* l) {
    __builtin_amdgcn_global_load_lds(
        (const __attribute__((address_space(1))) void*)g,
        (__attribute__((address_space(3))) void*)l, 16, 0, 0);
}

__device__ __forceinline__ float gelu_f(float v) {
    float u = 0.7978845608028654f * (v + 0.044715f * v * v * v);
    return 0.5f * v * (1.0f + tanhf(u));
}

__device__ __forceinline__ float block_sum_256(float v, float* sh) {
    #pragma unroll
    for (int off = 32; off > 0; off >>= 1) v += __shfl_down(v, off, 64);
    const int lane = threadIdx.x & 63, w = threadIdx.x >> 6;
    __syncthreads();
    if (lane == 0) sh[w] = v;
    __syncthreads();
    return sh[0] + sh[1] + sh[2] + sh[3];
}

// ---------------------------------------------------------------- gather (bf16 out)
__global__ __launch_bounds__(128) void gather_kernel(
    const int* __restrict__ ids, const float* __restrict__ table,
    const float* __restrict__ pop, __hip_bfloat16* __restrict__ sebf,
    float* __restrict__ debias) {
    const int k = blockIdx.x, t = threadIdx.x;
    const int id = ids[k];
    float4 v = reinterpret_cast<const float4*>(table + (size_t)id * DIM)[t];
    __hip_bfloat16* dst = sebf + (size_t)k * DIM + t * 4;
    dst[0] = __float2bfloat16(v.x);
    dst[1] = __float2bfloat16(v.y);
    dst[2] = __float2bfloat16(v.z);
    dst[3] = __float2bfloat16(v.w);
    if (t == 0) debias[k] = logf(pop[id]);
}

// ---------------------------------------------------------------- masks
__global__ __launch_bounds__(256) void mask_kernel(
    const int* __restrict__ ids, const float* __restrict__ log_mask,
    uint8_t* __restrict__ colmask, uint8_t* __restrict__ padcol) {
    const int bi = blockIdx.x >> 3, seg = blockIdx.x & 7;
    __shared__ int sid[65];
    if (threadIdx.x < 65) sid[threadIdx.x] = ids[bi * 65 + threadIdx.x];
    __syncthreads();
    const int kend = (seg + 1) * (NCOL / 8);
    for (int k = seg * (NCOL / 8) + threadIdx.x; k < kend; k += 256) {
        const int id = ids[k];
        bool mem = false;
        #pragma unroll
        for (int j = 0; j < 65; j++) mem |= (sid[j] == id);
        const int i2 = k / 65, jj = k - i2 * 65;
        const bool pc = (jj < 64) && (log_mask[i2 * 64 + jj] == 0.0f);
        colmask[(size_t)bi * NCOL + k] = (mem || pc) ? 1 : 0;
        if (bi == 0) padcol[k] = pc ? 1 : 0;
    }
}

// ---------------------------------------------------------------- weight transpose+cast
// W[K][N] fp32 -> WT[N][K] bf16
__global__ __launch_bounds__(256) void transpose_bf16_kernel(
    const float* __restrict__ W, __hip_bfloat16* __restrict__ WT, int K, int N) {
    __shared__ float tile[32][33];
    const int nt = blockIdx.x * 32, kt = blockIdx.y * 32;
    const int c = threadIdx.x & 31, r = threadIdx.x >> 5;
    #pragma unroll
    for (int p = 0; p < 4; p++)
        tile[p * 8 + r][c] = W[(size_t)(kt + p * 8 + r) * N + nt + c];
    __syncthreads();
    #pragma unroll
    for (int p = 0; p < 4; p++)
        WT[(size_t)(nt + p * 8 + r) * K + kt + c] = __float2bfloat16(tile[c][p * 8 + r]);
}

// ---------------------------------------------------------------- LN kernels
__global__ __launch_bounds__(256) void add_pos_ln_kernel(
    const __hip_bfloat16* __restrict__ sebf, const float* __restrict__ pos,
    float* __restrict__ x, __hip_bfloat16* __restrict__ xb) {
    __shared__ float sh[4];
    const int r = blockIdx.x, b = r >> 6, s = r & 63, t = threadIdx.x;
    const __hip_bfloat16* src = sebf + ((size_t)b * 65 + s) * DIM;
    const float* pp = pos + (size_t)s * DIM;
    float v0 = __bfloat162float(src[t])       + pp[t];
    float v1 = __bfloat162float(src[t + 256]) + pp[t + 256];
    float sum = block_sum_256(v0 + v1, sh);
    float sq  = block_sum_256(v0 * v0 + v1 * v1, sh);
    float mean = sum * (1.0f / 512.0f);
    float var  = sq  * (1.0f / 512.0f) - mean * mean;
    float rs = rsqrtf(var + 1e-5f);
    float o0 = (v0 - mean) * rs, o1 = (v1 - mean) * rs;
    x[(size_t)r * DIM + t]       = o0;
    x[(size_t)r * DIM + t + 256] = o1;
    xb[(size_t)r * DIM + t]       = __float2bfloat16(o0);
    xb[(size_t)r * DIM + t + 256] = __float2bfloat16(o1);
}

__global__ __launch_bounds__(256) void resid_ln_kernel(
    float* __restrict__ x, const __hip_bfloat16* __restrict__ y,
    __hip_bfloat16* __restrict__ xb) {
    __shared__ float sh[4];
    const int r = blockIdx.x, t = threadIdx.x;
    float* xr = x + (size_t)r * DIM;
    const __hip_bfloat16* yr = y + (size_t)r * DIM;
    float v0 = xr[t]       + __bfloat162float(yr[t]);
    float v1 = xr[t + 256] + __bfloat162float(yr[t + 256]);
    float sum = block_sum_256(v0 + v1, sh);
    float sq  = block_sum_256(v0 * v0 + v1 * v1, sh);
    float mean = sum * (1.0f / 512.0f);
    float var  = sq  * (1.0f / 512.0f) - mean * mean;
    float rs = rsqrtf(var + 1e-5f);
    float o0 = (v0 - mean) * rs, o1 = (v1 - mean) * rs;
    xr[t] = o0; xr[t + 256] = o1;
    xb[(size_t)r * DIM + t]       = __float2bfloat16(o0);
    xb[(size_t)r * DIM + t + 256] = __float2bfloat16(o1);
}

// ---------------------------------------------------------------- bf16 MFMA GEMM (B^T)
// C[M,N] = A[M,K] * Bt[N,K]^T, all bf16. 128x128 tile, BK=32, 4 waves (2x2 of 64x64).
__global__ __launch_bounds__(256) void gemm_bt_kernel(
    const __hip_bfloat16* __restrict__ A, const __hip_bfloat16* __restrict__ Bt,
    __hip_bfloat16* __restrict__ C, int N, int K, int gelu_flag) {
    __shared__ uint16_t As[128 * 32];
    __shared__ uint16_t Bs[128 * 32];
    const int tid = threadIdx.x, w = tid >> 6, lane = tid & 63;
    const int wr = w >> 1, wc = w & 1;
    const int row0 = blockIdx.y * 128, col0 = blockIdx.x * 128;
    const uint16_t* Ag = (const uint16_t*)A;
    const uint16_t* Bg = (const uint16_t*)Bt;
    const int la4 = lane >> 2, lk = (lane & 3) * 8;
    f32x4 acc[4][4];
    #pragma unroll
    for (int i = 0; i < 4; i++)
        #pragma unroll
        for (int j = 0; j < 4; j++) acc[i][j] = {0.f, 0.f, 0.f, 0.f};

    for (int k0 = 0; k0 < K; k0 += 32) {
        #pragma unroll
        for (int i = 0; i < 2; i++) {
            const int rbase = w * 32 + i * 16;
            async_copy16(Ag + (size_t)(row0 + rbase + la4) * K + k0 + lk, &As[rbase * 32]);
            async_copy16(Bg + (size_t)(col0 + rbase + la4) * K + k0 + lk, &Bs[rbase * 32]);
        }
        __syncthreads();
        bf16x8 af[4], bfr[4];
        #pragma unroll
        for (int i = 0; i < 4; i++) {
            af[i]  = *(const bf16x8*)&As[(wr * 64 + i * 16 + (lane & 15)) * 32 + (lane >> 4) * 8];
            bfr[i] = *(const bf16x8*)&Bs[(wc * 64 + i * 16 + (lane & 15)) * 32 + (lane >> 4) * 8];
        }
        #pragma unroll
        for (int i = 0; i < 4; i++)
            #pragma unroll
            for (int j = 0; j < 4; j++)
                acc[i][j] = __builtin_amdgcn_mfma_f32_16x16x32_bf16(af[i], bfr[j], acc[i][j], 0, 0, 0);
        __syncthreads();
    }
    #pragma unroll
    for (int i = 0; i < 4; i++) {
        #pragma unroll
        for (int r = 0; r < 4; r++) {
            const int row = row0 + wr * 64 + i * 16 + (lane >> 4) * 4 + r;
            #pragma unroll
            for (int j = 0; j < 4; j++) {
                const int col = col0 + wc * 64 + j * 16 + (lane & 15);
                float v = acc[i][j][r];
                if (gelu_flag) v = gelu_f(v);
                C[(size_t)row * N + col] = __float2bfloat16(v);
            }
        }
    }
}

// ---------------------------------------------------------------- attention (per b,h)
__global__ __launch_bounds__(256) void attn_kernel(
    const __hip_bfloat16* __restrict__ qkv, const float* __restrict__ log_mask,
    __hip_bfloat16* __restrict__ obuf) {
    const int b = blockIdx.x >> 3, h = blockIdx.x & 7;
    __shared__ float QV[64][64];
    __shared__ float Ks[64][65];
    __shared__ float P[64][64];
    const int tid = threadIdx.x;
    const int w = tid >> 6, lane = tid & 63;
    #pragma unroll
    for (int p = 0; p < 16; p++) {
        int s = p * 4 + w;
        size_t base = (size_t)(b * 64 + s) * 1536 + h * 64 + lane;
        QV[s][lane] = __bfloat162float(qkv[base]);
        Ks[lane][s] = __bfloat162float(qkv[base + 512]);
    }
    __syncthreads();
    #pragma unroll
    for (int p = 0; p < 16; p++) {
        int q = p * 4 + w;
        float acc = 0.f;
        #pragma unroll
        for (int d = 0; d < 64; d++) acc += QV[q][d] * Ks[d][lane];
        bool ok = (lane <= q) && (log_mask[b * 64 + lane] != 0.0f);
        P[q][lane] = acc * 0.125f + (ok ? 0.0f : NEG_INF);
    }
    __syncthreads();
    #pragma unroll
    for (int p = 0; p < 16; p++) {
        int s = p * 4 + w;
        QV[s][lane] = __bfloat162float(qkv[(size_t)(b * 64 + s) * 1536 + 1024 + h * 64 + lane]);
    }
    #pragma unroll
    for (int p = 0; p < 16; p++) {
        int q = p * 4 + w;
        float v = P[q][lane];
        float m = v;
        #pragma unroll
        for (int off = 32; off > 0; off >>= 1) m = fmaxf(m, __shfl_xor(m, off, 64));
        float e = expf(v - m);
        float s = e;
        #pragma unroll
        for (int off = 32; off > 0; off >>= 1) s += __shfl_xor(s, off, 64);
        P[q][lane] = e / s;
    }
    __syncthreads();
    #pragma unroll
    for (int p = 0; p < 16; p++) {
        int q = p * 4 + w;
        float acc = 0.f;
        #pragma unroll
        for (int k = 0; k < 64; k++) acc += P[q][k] * QV[k][lane];
        obuf[(size_t)(b * 64 + q) * 512 + h * 64 + lane] = __float2bfloat16(acc);
    }
}

// ---------------------------------------------------------------- fused logits (MFMA + online softmax)
// grid: x = 65 col-blocks of 128, y = 64 row-blocks of 128
__global__ __launch_bounds__(256) void logits_kernel(
    const __hip_bfloat16* __restrict__ A, const __hip_bfloat16* __restrict__ Bt,
    const float* __restrict__ debias, const uint8_t* __restrict__ colmask,
    const uint8_t* __restrict__ padcol,
    float* __restrict__ partials, float* __restrict__ label_logit) {
    __shared__ uint16_t As[128 * 32];
    __shared__ uint16_t Bs[128 * 32];
    __shared__ float deb_s[128];
    __shared__ uint8_t cm_s[2][128];
    __shared__ uint8_t pc_s[128];
    const int tid = threadIdx.x, w = tid >> 6, lane = tid & 63;
    const int wr = w >> 1, wc = w & 1;
    const int row0 = blockIdx.y * 128, col0 = blockIdx.x * 128;
    const uint16_t* Ag = (const uint16_t*)A;
    const uint16_t* Bg = (const uint16_t*)Bt;
    const int la4 = lane >> 2, lk = (lane & 3) * 8;

    if (tid < 128) {
        deb_s[tid] = debias[col0 + tid];
        pc_s[tid]  = padcol[col0 + tid];
        const int bi0 = row0 >> 6;
        cm_s[0][tid] = colmask[(size_t)bi0 * NCOL + col0 + tid];
        cm_s[1][tid] = colmask[(size_t)(bi0 + 1) * NCOL + col0 + tid];
    }

    f32x4 acc[4][4];
    #pragma unroll
    for (int i = 0; i < 4; i++)
        #pragma unroll
        for (int j = 0; j < 4; j++) acc[i][j] = {0.f, 0.f, 0.f, 0.f};

    for (int k0 = 0; k0 < DIM; k0 += 32) {
        #pragma unroll
        for (int i = 0; i < 2; i++) {
            const int rbase = w * 32 + i * 16;
            async_copy16(Ag + (size_t)(row0 + rbase + la4) * DIM + k0 + lk, &As[rbase * 32]);
            async_copy16(Bg + (size_t)(col0 + rbase + la4) * DIM + k0 + lk, &Bs[rbase * 32]);
        }
        __syncthreads();
        bf16x8 af[4], bfr[4];
        #pragma unroll
        for (int i = 0; i < 4; i++) {
            af[i]  = *(const bf16x8*)&As[(wr * 64 + i * 16 + (lane & 15)) * 32 + (lane >> 4) * 8];
            bfr[i] = *(const bf16x8*)&Bs[(wc * 64 + i * 16 + (lane & 15)) * 32 + (lane >> 4) * 8];
        }
        #pragma unroll
        for (int i = 0; i < 4; i++)
            #pragma unroll
            for (int j = 0; j < 4; j++)
                acc[i][j] = __builtin_amdgcn_mfma_f32_16x16x32_bf16(af[i], bfr[j], acc[i][j], 0, 0, 0);
        __syncthreads();
    }

    #pragma unroll
    for (int i = 0; i < 4; i++) {
        #pragma unroll
        for (int r = 0; r < 4; r++) {
            const int lrow = wr * 64 + i * 16 + (lane >> 4) * 4 + r;
            const int row = row0 + lrow;
            const int bi = row >> 6;
            const int label = bi * 65 + (row & 63) + 1;
            float vals[4];
            float vmax = -3.0e38f;
            #pragma unroll
            for (int j = 0; j < 4; j++) {
                const int lcol = wc * 64 + j * 16 + (lane & 15);
                const int col = col0 + lcol;
                float v = acc[i][j][r] - deb_s[lcol];
                const bool is_lab = (col == label);
                const bool masked = is_lab ? (pc_s[lcol] != 0) : (cm_s[lrow >> 6][lcol] != 0);
                if (masked) v = NEG_INF;
                if (is_lab) label_logit[row] = v;
                vals[j] = v;
                vmax = fmaxf(vmax, v);
            }
            #pragma unroll
            for (int off = 1; off < 16; off <<= 1) vmax = fmaxf(vmax, __shfl_xor(vmax, off, 64));
            float s = 0.f;
            #pragma unroll
            for (int j = 0; j < 4; j++) s += expf(vals[j] - vmax);
            #pragma unroll
            for (int off = 1; off < 16; off <<= 1) s += __shfl_xor(s, off, 64);
            if ((lane & 15) == 0) {
                const int strip = (col0 >> 6) + wc;           // 0..129
                const size_t idx = ((size_t)row * 130 + strip) * 2;
                partials[idx]     = vmax;
                partials[idx + 1] = s;
            }
        }
    }
}

// ---------------------------------------------------------------- combine + reduce
__global__ __launch_bounds__(256) void combine_kernel(
    const float* __restrict__ partials, const float* __restrict__ label_logit,
    const float* __restrict__ log_mask, float* __restrict__ bsums) {
    const int row = blockIdx.x * 256 + threadIdx.x;
    const float* p = partials + (size_t)row * 260;
    float M = -3.4e38f;
    for (int t = 0; t < 130; t++) M = fmaxf(M, p[2 * t]);
    float Ls = 0.f;
    for (int t = 0; t < 130; t++) Ls += p[2 * t + 1] * expf(p[2 * t] - M);
    const float lse = M + logf(Ls);
    const float valid = (log_mask[row] != 0.0f) ? 1.0f : 0.0f;
    float a = (lse - label_logit[row]) * valid;
    float c = valid;
    __shared__ float sa[4], sc[4];
    #pragma unroll
    for (int off = 32; off > 0; off >>= 1) {
        a += __shfl_down(a, off, 64);
        c += __shfl_down(c, off, 64);
    }
    const int lane = threadIdx.x & 63, w = threadIdx.x >> 6;
    if (lane == 0) { sa[w] = a; sc[w] = c; }
    __syncthreads();
    if (threadIdx.x == 0) {
        bsums[blockIdx.x * 2 + 0] = sa[0] + sa[1] + sa[2] + sa[3];
        bsums[blockIdx.x * 2 + 1] = sc[0] + sc[1] + sc[2] + sc[3];
    }
}

__global__ __launch_bounds__(64) void finalize_kernel(
    const float* __restrict__ bsums, float* __restrict__ out) {
    const int t = threadIdx.x;
    float a = 0.f, c = 0.f;
    if (t < 32) { a = bsums[2 * t]; c = bsums[2 * t + 1]; }
    #pragma unroll
    for (int off = 32; off > 0; off >>= 1) {
        a += __shfl_down(a, off, 64);
        c += __shfl_down(c, off, 64);
    }
    if (t == 0) out[0] = a / c;
}

// ---------------------------------------------------------------- launch
extern "C" void kernel_launch(void* const* d_in, const int* in_sizes, int n_in,
                              void* d_out, int out_size, void* d_ws, size_t ws_size,
                              hipStream_t stream) {
    const int*   ids    = (const int*)d_in[0];
    const float* lm     = (const float*)d_in[1];
    const float* emb    = (const float*)d_in[2];
    const float* pos    = (const float*)d_in[3];
    const float* qkv_w  = (const float*)d_in[4];
    const float* out_w  = (const float*)d_in[5];
    const float* ffn1_w = (const float*)d_in[6];
    const float* ffn2_w = (const float*)d_in[7];
    const float* pop    = (const float*)d_in[8];
    float* out = (float*)d_out;

    char* p = (char*)d_ws;
    auto alloc = [&](size_t bytes) {
        char* r = p;
        p += (bytes + 255) & ~(size_t)255;
        return r;
    };
    typedef __hip_bfloat16 bf16;
    bf16*    sebf     = (bf16*)alloc((size_t)NCOL * DIM * 2);        // 8.5 MB
    float*   debias   = (float*)alloc((size_t)NCOL * 4);
    uint8_t* padcol   = (uint8_t*)alloc(NCOL);
    uint8_t* colmask  = (uint8_t*)alloc((size_t)BSZ * NCOL);         // 1.06 MB
    float*   x        = (float*)alloc((size_t)NROW * DIM * 4);       // 16.8 MB
    bf16*    xb       = (bf16*)alloc((size_t)NROW * DIM * 2);        // 8.4 MB
    bf16*    big      = (bf16*)alloc((size_t)NROW * 2048 * 2);       // 33.6 MB (qkv / h)
    bf16*    tmp1     = (bf16*)alloc((size_t)NROW * DIM * 2);        // attn out
    bf16*    tmp2     = (bf16*)alloc((size_t)NROW * DIM * 2);        // proj / f2
    float*   partials = (float*)alloc((size_t)NROW * 130 * 2 * 4);   // 8.5 MB
    float*   lab      = (float*)alloc((size_t)NROW * 4);
    float*   bsums    = (float*)alloc(64 * 4);
    bf16*    qkvT     = (bf16*)alloc((size_t)NLAYER * 1536 * 512 * 2);
    bf16*    outT     = (bf16*)alloc((size_t)NLAYER * 512 * 512 * 2);
    bf16*    f1T      = (bf16*)alloc((size_t)NLAYER * 2048 * 512 * 2);
    bf16*    f2T      = (bf16*)alloc((size_t)NLAYER * 512 * 2048 * 2);

    // weight transpose+cast: W[K][N] -> WT[N][K] bf16
    for (int l = 0; l < NLAYER; l++) {
        transpose_bf16_kernel<<<dim3(1536 / 32, 512 / 32), 256, 0, stream>>>(
            qkv_w + (size_t)l * 512 * 1536, qkvT + (size_t)l * 1536 * 512, 512, 1536);
        transpose_bf16_kernel<<<dim3(512 / 32, 512 / 32), 256, 0, stream>>>(
            out_w + (size_t)l * 512 * 512, outT + (size_t)l * 512 * 512, 512, 512);
        transpose_bf16_kernel<<<dim3(2048 / 32, 512 / 32), 256, 0, stream>>>(
            ffn1_w + (size_t)l * 512 * 2048, f1T + (size_t)l * 2048 * 512, 512, 2048);
        transpose_bf16_kernel<<<dim3(512 / 32, 2048 / 32), 256, 0, stream>>>(
            ffn2_w + (size_t)l * 2048 * 512, f2T + (size_t)l * 512 * 2048, 2048, 512);
    }

    gather_kernel<<<NCOL, 128, 0, stream>>>(ids, emb, pop, sebf, debias);
    mask_kernel<<<BSZ * 8, 256, 0, stream>>>(ids, lm, colmask, padcol);
    add_pos_ln_kernel<<<NROW, 256, 0, stream>>>(sebf, pos, x, xb);

    for (int l = 0; l < NLAYER; l++) {
        gemm_bt_kernel<<<dim3(1536 / 128, NROW / 128), 256, 0, stream>>>(
            xb, qkvT + (size_t)l * 1536 * 512, big, 1536, 512, 0);
        attn_kernel<<<BSZ * HEADS, 256, 0, stream>>>(big, lm, tmp1);
        gemm_bt_kernel<<<dim3(512 / 128, NROW / 128), 256, 0, stream>>>(
            tmp1, outT + (size_t)l * 512 * 512, tmp2, 512, 512, 0);
        resid_ln_kernel<<<NROW, 256, 0, stream>>>(x, tmp2, xb);
        gemm_bt_kernel<<<dim3(2048 / 128, NROW / 128), 256, 0, stream>>>(
            xb, f1T + (size_t)l * 2048 * 512, big, 2048, 512, 1);
        gemm_bt_kernel<<<dim3(512 / 128, NROW / 128), 256, 0, stream>>>(
            big, f2T + (size_t)l * 512 * 2048, tmp2, 512, 2048, 0);
        resid_ln_kernel<<<NROW, 256, 0, stream>>>(x, tmp2, xb);
    }

    logits_kernel<<<dim3(NCOL / 128, NROW / 128), 256, 0, stream>>>(
        xb, sebf, debias, colmask, padcol, partials, lab);
    combine_kernel<<<NROW / 256, 256, 0, stream>>>(partials, lab, lm, bsums);
    finalize_kernel<<<1, 64, 0, stream>>>(bsums, out);
}

// Round 3
// 786.101 us; speedup vs baseline: 3.5583x; 1.1698x over previous
//
#include <hip/hip_runtime.h>
#include <hip/hip_bf16.h>
#include <cstdint>
#include <cstddef>

#define NEG_INF -10000.0f

constexpr int BSZ  = 128;
constexpr int SEQ  = 64;     // L
constexpr int DIM  = 512;    // D
constexpr int HEADS = 8;
constexpr int NLAYER = 2;
constexpr int NCOL = BSZ * (SEQ + 1);   // 8320
constexpr int NROW = BSZ * SEQ;         // 8192

typedef __attribute__((ext_vector_type(8))) short bf16x8;   // 8 bf16 in 4 VGPRs
typedef __attribute__((ext_vector_type(4))) short bf16x4;
typedef __attribute__((ext_vector_type(4))) float f32x4;

// async global->LDS, 16B per lane, dest = ldsbase + lane*16
__device__ __forceinline__ void async_copy16(const void* g, void* l) {
    __builtin_amdgcn_global_load_lds(
        (const __attribute__((address_space(1))) void*)g,
        (__attribute__((address_space(3))) void*)l, 16, 0, 0);
}

__device__ __forceinline__ float gelu_f(float v) {
    float u = 0.7978845608028654f * (v + 0.044715f * v * v * v);
    return 0.5f * v * (1.0f + tanhf(u));
}

__device__ __forceinline__ float block_sum_256(float v, float* sh) {
    #pragma unroll
    for (int off = 32; off > 0; off >>= 1) v += __shfl_down(v, off, 64);
    const int lane = threadIdx.x & 63, w = threadIdx.x >> 6;
    __syncthreads();
    if (lane == 0) sh[w] = v;
    __syncthreads();
    return sh[0] + sh[1] + sh[2] + sh[3];
}

// ---------------------------------------------------------------- gather (bf16 out)
__global__ __launch_bounds__(128) void gather_kernel(
    const int* __restrict__ ids, const float* __restrict__ table,
    const float* __restrict__ pop, __hip_bfloat16* __restrict__ sebf,
    float* __restrict__ debias) {
    const int k = blockIdx.x, t = threadIdx.x;
    const int id = ids[k];
    float4 v = reinterpret_cast<const float4*>(table + (size_t)id * DIM)[t];
    __hip_bfloat16* dst = sebf + (size_t)k * DIM + t * 4;
    dst[0] = __float2bfloat16(v.x);
    dst[1] = __float2bfloat16(v.y);
    dst[2] = __float2bfloat16(v.z);
    dst[3] = __float2bfloat16(v.w);
    if (t == 0) debias[k] = logf(pop[id]);
}

// ---------------------------------------------------------------- masks
__global__ __launch_bounds__(256) void mask_kernel(
    const int* __restrict__ ids, const float* __restrict__ log_mask,
    uint8_t* __restrict__ colmask, uint8_t* __restrict__ padcol) {
    const int bi = blockIdx.x >> 3, seg = blockIdx.x & 7;
    __shared__ int sid[65];
    if (threadIdx.x < 65) sid[threadIdx.x] = ids[bi * 65 + threadIdx.x];
    __syncthreads();
    const int kend = (seg + 1) * (NCOL / 8);
    for (int k = seg * (NCOL / 8) + threadIdx.x; k < kend; k += 256) {
        const int id = ids[k];
        bool mem = false;
        #pragma unroll
        for (int j = 0; j < 65; j++) mem |= (sid[j] == id);
        const int i2 = k / 65, jj = k - i2 * 65;
        const bool pc = (jj < 64) && (log_mask[i2 * 64 + jj] == 0.0f);
        colmask[(size_t)bi * NCOL + k] = (mem || pc) ? 1 : 0;
        if (bi == 0) padcol[k] = pc ? 1 : 0;
    }
}

// ---------------------------------------------------------------- weight transpose+cast
// W[K][N] fp32 -> WT[N][K] bf16; blockIdx.z = layer (stride K*N)
__global__ __launch_bounds__(256) void transpose_bf16_kernel(
    const float* __restrict__ W, __hip_bfloat16* __restrict__ WT, int K, int N) {
    __shared__ float tile[32][33];
    const size_t loff = (size_t)blockIdx.z * K * N;
    const int nt = blockIdx.x * 32, kt = blockIdx.y * 32;
    const int c = threadIdx.x & 31, r = threadIdx.x >> 5;
    #pragma unroll
    for (int p = 0; p < 4; p++)
        tile[p * 8 + r][c] = W[loff + (size_t)(kt + p * 8 + r) * N + nt + c];
    __syncthreads();
    #pragma unroll
    for (int p = 0; p < 4; p++)
        WT[loff + (size_t)(nt + p * 8 + r) * K + kt + c] = __float2bfloat16(tile[c][p * 8 + r]);
}

// ---------------------------------------------------------------- LN kernels
__global__ __launch_bounds__(256) void add_pos_ln_kernel(
    const __hip_bfloat16* __restrict__ sebf, const float* __restrict__ pos,
    float* __restrict__ x, __hip_bfloat16* __restrict__ xb) {
    __shared__ float sh[4];
    const int r = blockIdx.x, b = r >> 6, s = r & 63, t = threadIdx.x;
    const __hip_bfloat16* src = sebf + ((size_t)b * 65 + s) * DIM;
    const float* pp = pos + (size_t)s * DIM;
    float v0 = __bfloat162float(src[t])       + pp[t];
    float v1 = __bfloat162float(src[t + 256]) + pp[t + 256];
    float sum = block_sum_256(v0 + v1, sh);
    float sq  = block_sum_256(v0 * v0 + v1 * v1, sh);
    float mean = sum * (1.0f / 512.0f);
    float var  = sq  * (1.0f / 512.0f) - mean * mean;
    float rs = rsqrtf(var + 1e-5f);
    float o0 = (v0 - mean) * rs, o1 = (v1 - mean) * rs;
    x[(size_t)r * DIM + t]       = o0;
    x[(size_t)r * DIM + t + 256] = o1;
    xb[(size_t)r * DIM + t]       = __float2bfloat16(o0);
    xb[(size_t)r * DIM + t + 256] = __float2bfloat16(o1);
}

__global__ __launch_bounds__(256) void resid_ln_kernel(
    float* __restrict__ x, const __hip_bfloat16* __restrict__ y,
    __hip_bfloat16* __restrict__ xb) {
    __shared__ float sh[4];
    const int r = blockIdx.x, t = threadIdx.x;
    float* xr = x + (size_t)r * DIM;
    const __hip_bfloat16* yr = y + (size_t)r * DIM;
    float v0 = xr[t]       + __bfloat162float(yr[t]);
    float v1 = xr[t + 256] + __bfloat162float(yr[t + 256]);
    float sum = block_sum_256(v0 + v1, sh);
    float sq  = block_sum_256(v0 * v0 + v1 * v1, sh);
    float mean = sum * (1.0f / 512.0f);
    float var  = sq  * (1.0f / 512.0f) - mean * mean;
    float rs = rsqrtf(var + 1e-5f);
    float o0 = (v0 - mean) * rs, o1 = (v1 - mean) * rs;
    xr[t] = o0; xr[t + 256] = o1;
    xb[(size_t)r * DIM + t]       = __float2bfloat16(o0);
    xb[(size_t)r * DIM + t + 256] = __float2bfloat16(o1);
}

// ---------------------------------------------------------------- bf16 MFMA GEMM (B^T)
// C[M,N] = A[M,K] * Bt[N,K]^T, all bf16. Tile 128 x TN, BK=32, 4 waves.
// TN=128: waves 2x2 (each 64x64). TN=64: waves 4x1 (each 32x64).
template<int TN, bool GELU>
__global__ __launch_bounds__(256) void gemm_bt_kernel(
    const __hip_bfloat16* __restrict__ A, const __hip_bfloat16* __restrict__ Bt,
    __hip_bfloat16* __restrict__ C, int N, int K) {
    __shared__ uint16_t As[128 * 32];
    __shared__ uint16_t Bs[TN * 32];
    const int tid = threadIdx.x, w = tid >> 6, lane = tid & 63;
    constexpr int AI = (TN == 128) ? 4 : 2;          // 16-row tiles per wave
    const int wr = (TN == 128) ? (w >> 1) : w;
    const int wc = (TN == 128) ? (w & 1) : 0;
    const int rowbase = wr * (AI * 16);
    const int row0 = blockIdx.y * 128, col0 = blockIdx.x * TN;
    const uint16_t* Ag = (const uint16_t*)A;
    const uint16_t* Bg = (const uint16_t*)Bt;
    const int la4 = lane >> 2, lk = (lane & 3) * 8;
    f32x4 acc[AI][4];
    #pragma unroll
    for (int i = 0; i < AI; i++)
        #pragma unroll
        for (int j = 0; j < 4; j++) acc[i][j] = {0.f, 0.f, 0.f, 0.f};

    for (int k0 = 0; k0 < K; k0 += 32) {
        #pragma unroll
        for (int i = 0; i < 2; i++) {
            const int rbase = w * 32 + i * 16;
            async_copy16(Ag + (size_t)(row0 + rbase + la4) * K + k0 + lk, &As[rbase * 32]);
        }
        if (TN == 128) {
            #pragma unroll
            for (int i = 0; i < 2; i++) {
                const int rbase = w * 32 + i * 16;
                async_copy16(Bg + (size_t)(col0 + rbase + la4) * K + k0 + lk, &Bs[rbase * 32]);
            }
        } else {
            const int rbase = w * 16;
            async_copy16(Bg + (size_t)(col0 + rbase + la4) * K + k0 + lk, &Bs[rbase * 32]);
        }
        __syncthreads();
        bf16x8 af[AI], bfr[4];
        #pragma unroll
        for (int i = 0; i < AI; i++)
            af[i] = *(const bf16x8*)&As[(rowbase + i * 16 + (lane & 15)) * 32 + (lane >> 4) * 8];
        #pragma unroll
        for (int j = 0; j < 4; j++)
            bfr[j] = *(const bf16x8*)&Bs[(wc * 64 + j * 16 + (lane & 15)) * 32 + (lane >> 4) * 8];
        #pragma unroll
        for (int i = 0; i < AI; i++)
            #pragma unroll
            for (int j = 0; j < 4; j++)
                acc[i][j] = __builtin_amdgcn_mfma_f32_16x16x32_bf16(af[i], bfr[j], acc[i][j], 0, 0, 0);
        __syncthreads();
    }
    #pragma unroll
    for (int i = 0; i < AI; i++) {
        #pragma unroll
        for (int r = 0; r < 4; r++) {
            const int row = row0 + rowbase + i * 16 + (lane >> 4) * 4 + r;
            #pragma unroll
            for (int j = 0; j < 4; j++) {
                const int col = col0 + wc * 64 + j * 16 + (lane & 15);
                float v = acc[i][j][r];
                if (GELU) v = gelu_f(v);
                C[(size_t)row * N + col] = __float2bfloat16(v);
            }
        }
    }
}

// ---------------------------------------------------------------- MFMA attention (per b,h)
// S = Q@K^T (K rows are already B^T layout); softmax in C-layout regs; P->LDS;
// O = P@V with strided V B-frags. Strides padded to break bank aliasing.
__global__ __launch_bounds__(256) void attn_mfma_kernel(
    const __hip_bfloat16* __restrict__ qkv, const float* __restrict__ log_mask,
    __hip_bfloat16* __restrict__ obuf) {
    constexpr int QS = 72;   // Q/K/P LDS row stride (16B-aligned, banks spread)
    constexpr int VS = 68;   // V LDS row stride (8B-aligned)
    __shared__ uint16_t Qs[64 * QS];
    __shared__ uint16_t Ks_[64 * QS];
    __shared__ uint16_t Ps[64 * QS];
    __shared__ uint16_t Vs[64 * VS];
    __shared__ float mask_s[64];
    const int b = blockIdx.x >> 3, h = blockIdx.x & 7;
    const int tid = threadIdx.x, w = tid >> 6, lane = tid & 63;
    const int quad = lane >> 4, l15 = lane & 15;
    const uint16_t* qg = (const uint16_t*)qkv;

    if (tid < 64) mask_s[tid] = log_mask[b * 64 + tid];
    // stage Q,K (row-major, stride QS) and V (row-major, stride VS)
    #pragma unroll
    for (int it = 0; it < 2; it++) {
        const int idx = it * 256 + tid;          // 0..511
        const int s = idx >> 3, c = (idx & 7) * 8;
        const size_t gbase = (size_t)(b * 64 + s) * 1536 + h * 64 + c;
        *(bf16x8*)&Qs[s * QS + c]  = *(const bf16x8*)&qg[gbase];
        *(bf16x8*)&Ks_[s * QS + c] = *(const bf16x8*)&qg[gbase + 512];
        bf16x8 vv = *(const bf16x8*)&qg[gbase + 1024];
        *(bf16x4*)&Vs[s * VS + c]     = bf16x4{vv[0], vv[1], vv[2], vv[3]};
        *(bf16x4*)&Vs[s * VS + c + 4] = bf16x4{vv[4], vv[5], vv[6], vv[7]};
    }
    __syncthreads();

    // ---- S = Q K^T for rows w*16..w*16+15 (one 16-row strip per wave)
    f32x4 sacc[4];
    #pragma unroll
    for (int j = 0; j < 4; j++) sacc[j] = {0.f, 0.f, 0.f, 0.f};
    #pragma unroll
    for (int k0 = 0; k0 < 2; k0++) {
        bf16x8 aq = *(const bf16x8*)&Qs[(w * 16 + l15) * QS + k0 * 32 + quad * 8];
        #pragma unroll
        for (int j = 0; j < 4; j++) {
            bf16x8 bk = *(const bf16x8*)&Ks_[(j * 16 + l15) * QS + k0 * 32 + quad * 8];
            sacc[j] = __builtin_amdgcn_mfma_f32_16x16x32_bf16(aq, bk, sacc[j], 0, 0, 0);
        }
    }
    // ---- softmax per row (C layout: col = j*16+l15, row = quad*4+r), P -> LDS bf16
    #pragma unroll
    for (int r = 0; r < 4; r++) {
        const int q = w * 16 + quad * 4 + r;
        float vals[4];
        float vmax = -3.0e38f;
        #pragma unroll
        for (int j = 0; j < 4; j++) {
            const int col = j * 16 + l15;
            const bool ok = (col <= q) && (mask_s[col] != 0.0f);
            float v = sacc[j][r] * 0.125f + (ok ? 0.0f : NEG_INF);
            vals[j] = v;
            vmax = fmaxf(vmax, v);
        }
        #pragma unroll
        for (int off = 1; off < 16; off <<= 1) vmax = fmaxf(vmax, __shfl_xor(vmax, off, 64));
        float e[4], s = 0.f;
        #pragma unroll
        for (int j = 0; j < 4; j++) { e[j] = expf(vals[j] - vmax); s += e[j]; }
        #pragma unroll
        for (int off = 1; off < 16; off <<= 1) s += __shfl_xor(s, off, 64);
        const float inv = 1.0f / s;
        #pragma unroll
        for (int j = 0; j < 4; j++) {
            __hip_bfloat16 pb = __float2bfloat16(e[j] * inv);
            Ps[q * QS + j * 16 + l15] = *(uint16_t*)&pb;
        }
    }
    __syncthreads();

    // ---- O = P V  (A = P rows w*16.., B[n=d][k=s] = V[s][d] strided reads)
    f32x4 oacc[4];
    #pragma unroll
    for (int j = 0; j < 4; j++) oacc[j] = {0.f, 0.f, 0.f, 0.f};
    #pragma unroll
    for (int k0 = 0; k0 < 2; k0++) {
        bf16x8 ap = *(const bf16x8*)&Ps[(w * 16 + l15) * QS + k0 * 32 + quad * 8];
        #pragma unroll
        for (int j = 0; j < 4; j++) {
            bf16x8 bv;
            #pragma unroll
            for (int jj = 0; jj < 8; jj++)
                bv[jj] = (short)Vs[(k0 * 32 + quad * 8 + jj) * VS + j * 16 + l15];
            oacc[j] = __builtin_amdgcn_mfma_f32_16x16x32_bf16(ap, bv, oacc[j], 0, 0, 0);
        }
    }
    #pragma unroll
    for (int r = 0; r < 4; r++) {
        const int q = w * 16 + quad * 4 + r;
        #pragma unroll
        for (int j = 0; j < 4; j++) {
            const int d = j * 16 + l15;
            obuf[(size_t)(b * 64 + q) * 512 + h * 64 + d] = __float2bfloat16(oacc[j][r]);
        }
    }
}

// ---------------------------------------------------------------- fused logits (MFMA + online softmax)
__global__ __launch_bounds__(256) void logits_kernel(
    const __hip_bfloat16* __restrict__ A, const __hip_bfloat16* __restrict__ Bt,
    const float* __restrict__ debias, const uint8_t* __restrict__ colmask,
    const uint8_t* __restrict__ padcol,
    float* __restrict__ partials, float* __restrict__ label_logit) {
    __shared__ uint16_t As[128 * 32];
    __shared__ uint16_t Bs[128 * 32];
    __shared__ float deb_s[128];
    __shared__ uint8_t cm_s[2][128];
    __shared__ uint8_t pc_s[128];
    const int tid = threadIdx.x, w = tid >> 6, lane = tid & 63;
    const int wr = w >> 1, wc = w & 1;
    const int row0 = blockIdx.y * 128, col0 = blockIdx.x * 128;
    const uint16_t* Ag = (const uint16_t*)A;
    const uint16_t* Bg = (const uint16_t*)Bt;
    const int la4 = lane >> 2, lk = (lane & 3) * 8;

    if (tid < 128) {
        deb_s[tid] = debias[col0 + tid];
        pc_s[tid]  = padcol[col0 + tid];
        const int bi0 = row0 >> 6;
        cm_s[0][tid] = colmask[(size_t)bi0 * NCOL + col0 + tid];
        cm_s[1][tid] = colmask[(size_t)(bi0 + 1) * NCOL + col0 + tid];
    }

    f32x4 acc[4][4];
    #pragma unroll
    for (int i = 0; i < 4; i++)
        #pragma unroll
        for (int j = 0; j < 4; j++) acc[i][j] = {0.f, 0.f, 0.f, 0.f};

    for (int k0 = 0; k0 < DIM; k0 += 32) {
        #pragma unroll
        for (int i = 0; i < 2; i++) {
            const int rbase = w * 32 + i * 16;
            async_copy16(Ag + (size_t)(row0 + rbase + la4) * DIM + k0 + lk, &As[rbase * 32]);
            async_copy16(Bg + (size_t)(col0 + rbase + la4) * DIM + k0 + lk, &Bs[rbase * 32]);
        }
        __syncthreads();
        bf16x8 af[4], bfr[4];
        #pragma unroll
        for (int i = 0; i < 4; i++) {
            af[i]  = *(const bf16x8*)&As[(wr * 64 + i * 16 + (lane & 15)) * 32 + (lane >> 4) * 8];
            bfr[i] = *(const bf16x8*)&Bs[(wc * 64 + i * 16 + (lane & 15)) * 32 + (lane >> 4) * 8];
        }
        #pragma unroll
        for (int i = 0; i < 4; i++)
            #pragma unroll
            for (int j = 0; j < 4; j++)
                acc[i][j] = __builtin_amdgcn_mfma_f32_16x16x32_bf16(af[i], bfr[j], acc[i][j], 0, 0, 0);
        __syncthreads();
    }

    #pragma unroll
    for (int i = 0; i < 4; i++) {
        #pragma unroll
        for (int r = 0; r < 4; r++) {
            const int lrow = wr * 64 + i * 16 + (lane >> 4) * 4 + r;
            const int row = row0 + lrow;
            const int bi = row >> 6;
            const int label = bi * 65 + (row & 63) + 1;
            float vals[4];
            float vmax = -3.0e38f;
            #pragma unroll
            for (int j = 0; j < 4; j++) {
                const int lcol = wc * 64 + j * 16 + (lane & 15);
                const int col = col0 + lcol;
                float v = acc[i][j][r] - deb_s[lcol];
                const bool is_lab = (col == label);
                const bool masked = is_lab ? (pc_s[lcol] != 0) : (cm_s[lrow >> 6][lcol] != 0);
                if (masked) v = NEG_INF;
                if (is_lab) label_logit[row] = v;
                vals[j] = v;
                vmax = fmaxf(vmax, v);
            }
            #pragma unroll
            for (int off = 1; off < 16; off <<= 1) vmax = fmaxf(vmax, __shfl_xor(vmax, off, 64));
            float s = 0.f;
            #pragma unroll
            for (int j = 0; j < 4; j++) s += expf(vals[j] - vmax);
            #pragma unroll
            for (int off = 1; off < 16; off <<= 1) s += __shfl_xor(s, off, 64);
            if ((lane & 15) == 0) {
                const int strip = (col0 >> 6) + wc;           // 0..129
                const size_t idx = ((size_t)row * 130 + strip) * 2;
                partials[idx]     = vmax;
                partials[idx + 1] = s;
            }
        }
    }
}

// ---------------------------------------------------------------- combine + reduce
__global__ __launch_bounds__(256) void combine_kernel(
    const float* __restrict__ partials, const float* __restrict__ label_logit,
    const float* __restrict__ log_mask, float* __restrict__ bsums) {
    const int row = blockIdx.x * 256 + threadIdx.x;
    const float* p = partials + (size_t)row * 260;
    float M = -3.4e38f;
    for (int t = 0; t < 130; t++) M = fmaxf(M, p[2 * t]);
    float Ls = 0.f;
    for (int t = 0; t < 130; t++) Ls += p[2 * t + 1] * expf(p[2 * t] - M);
    const float lse = M + logf(Ls);
    const float valid = (log_mask[row] != 0.0f) ? 1.0f : 0.0f;
    float a = (lse - label_logit[row]) * valid;
    float c = valid;
    __shared__ float sa[4], sc[4];
    #pragma unroll
    for (int off = 32; off > 0; off >>= 1) {
        a += __shfl_down(a, off, 64);
        c += __shfl_down(c, off, 64);
    }
    const int lane = threadIdx.x & 63, w = threadIdx.x >> 6;
    if (lane == 0) { sa[w] = a; sc[w] = c; }
    __syncthreads();
    if (threadIdx.x == 0) {
        bsums[blockIdx.x * 2 + 0] = sa[0] + sa[1] + sa[2] + sa[3];
        bsums[blockIdx.x * 2 + 1] = sc[0] + sc[1] + sc[2] + sc[3];
    }
}

__global__ __launch_bounds__(64) void finalize_kernel(
    const float* __restrict__ bsums, float* __restrict__ out) {
    const int t = threadIdx.x;
    float a = 0.f, c = 0.f;
    if (t < 32) { a = bsums[2 * t]; c = bsums[2 * t + 1]; }
    #pragma unroll
    for (int off = 32; off > 0; off >>= 1) {
        a += __shfl_down(a, off, 64);
        c += __shfl_down(c, off, 64);
    }
    if (t == 0) out[0] = a / c;
}

// ---------------------------------------------------------------- launch
extern "C" void kernel_launch(void* const* d_in, const int* in_sizes, int n_in,
                              void* d_out, int out_size, void* d_ws, size_t ws_size,
                              hipStream_t stream) {
    const int*   ids    = (const int*)d_in[0];
    const float* lm     = (const float*)d_in[1];
    const float* emb    = (const float*)d_in[2];
    const float* pos    = (const float*)d_in[3];
    const float* qkv_w  = (const float*)d_in[4];
    const float* out_w  = (const float*)d_in[5];
    const float* ffn1_w = (const float*)d_in[6];
    const float* ffn2_w = (const float*)d_in[7];
    const float* pop    = (const float*)d_in[8];
    float* out = (float*)d_out;

    char* p = (char*)d_ws;
    auto alloc = [&](size_t bytes) {
        char* r = p;
        p += (bytes + 255) & ~(size_t)255;
        return r;
    };
    typedef __hip_bfloat16 bf16;
    bf16*    sebf     = (bf16*)alloc((size_t)NCOL * DIM * 2);        // 8.5 MB
    float*   debias   = (float*)alloc((size_t)NCOL * 4);
    uint8_t* padcol   = (uint8_t*)alloc(NCOL);
    uint8_t* colmask  = (uint8_t*)alloc((size_t)BSZ * NCOL);         // 1.06 MB
    float*   x        = (float*)alloc((size_t)NROW * DIM * 4);       // 16.8 MB
    bf16*    xb       = (bf16*)alloc((size_t)NROW * DIM * 2);        // 8.4 MB
    bf16*    big      = (bf16*)alloc((size_t)NROW * 2048 * 2);       // 33.6 MB (qkv / h)
    bf16*    tmp1     = (bf16*)alloc((size_t)NROW * DIM * 2);        // attn out
    bf16*    tmp2     = (bf16*)alloc((size_t)NROW * DIM * 2);        // proj / f2
    float*   partials = (float*)alloc((size_t)NROW * 130 * 2 * 4);   // 8.5 MB
    float*   lab      = (float*)alloc((size_t)NROW * 4);
    float*   bsums    = (float*)alloc(64 * 4);
    bf16*    qkvT     = (bf16*)alloc((size_t)NLAYER * 1536 * 512 * 2);
    bf16*    outT     = (bf16*)alloc((size_t)NLAYER * 512 * 512 * 2);
    bf16*    f1T      = (bf16*)alloc((size_t)NLAYER * 2048 * 512 * 2);
    bf16*    f2T      = (bf16*)alloc((size_t)NLAYER * 512 * 2048 * 2);

    // weight transpose+cast: W[K][N] -> WT[N][K] bf16, all layers per launch
    transpose_bf16_kernel<<<dim3(1536 / 32, 512 / 32, NLAYER), 256, 0, stream>>>(
        qkv_w, qkvT, 512, 1536);
    transpose_bf16_kernel<<<dim3(512 / 32, 512 / 32, NLAYER), 256, 0, stream>>>(
        out_w, outT, 512, 512);
    transpose_bf16_kernel<<<dim3(2048 / 32, 512 / 32, NLAYER), 256, 0, stream>>>(
        ffn1_w, f1T, 512, 2048);
    transpose_bf16_kernel<<<dim3(512 / 32, 2048 / 32, NLAYER), 256, 0, stream>>>(
        ffn2_w, f2T, 2048, 512);

    gather_kernel<<<NCOL, 128, 0, stream>>>(ids, emb, pop, sebf, debias);
    mask_kernel<<<BSZ * 8, 256, 0, stream>>>(ids, lm, colmask, padcol);
    add_pos_ln_kernel<<<NROW, 256, 0, stream>>>(sebf, pos, x, xb);

    for (int l = 0; l < NLAYER; l++) {
        gemm_bt_kernel<128, false><<<dim3(1536 / 128, NROW / 128), 256, 0, stream>>>(
            xb, qkvT + (size_t)l * 1536 * 512, big, 1536, 512);
        attn_mfma_kernel<<<BSZ * HEADS, 256, 0, stream>>>(big, lm, tmp1);
        gemm_bt_kernel<64, false><<<dim3(512 / 64, NROW / 128), 256, 0, stream>>>(
            tmp1, outT + (size_t)l * 512 * 512, tmp2, 512, 512);
        resid_ln_kernel<<<NROW, 256, 0, stream>>>(x, tmp2, xb);
        gemm_bt_kernel<128, true><<<dim3(2048 / 128, NROW / 128), 256, 0, stream>>>(
            xb, f1T + (size_t)l * 2048 * 512, big, 2048, 512);
        gemm_bt_kernel<64, false><<<dim3(512 / 64, NROW / 128), 256, 0, stream>>>(
            big, f2T + (size_t)l * 512 * 2048, tmp2, 512, 2048);
        resid_ln_kernel<<<NROW, 256, 0, stream>>>(x, tmp2, xb);
    }

    logits_kernel<<<dim3(NCOL / 128, NROW / 128), 256, 0, stream>>>(
        xb, sebf, debias, colmask, padcol, partials, lab);
    combine_kernel<<<NROW / 256, 256, 0, stream>>>(partials, lab, lm, bsums);
    finalize_kernel<<<1, 64, 0, stream>>>(bsums, out);
}

// Round 4
// 755.029 us; speedup vs baseline: 3.7048x; 1.0412x over previous
//
#include <hip/hip_runtime.h>
#include <hip/hip_bf16.h>
#include <cstdint>
#include <cstddef>

#define NEG_INF -10000.0f

constexpr int BSZ  = 128;
constexpr int SEQ  = 64;     // L
constexpr int DIM  = 512;    // D
constexpr int HEADS = 8;
constexpr int NLAYER = 2;
constexpr int NCOL = BSZ * (SEQ + 1);   // 8320
constexpr int NROW = BSZ * SEQ;         // 8192

typedef __attribute__((ext_vector_type(8))) short bf16x8;   // 8 bf16 in 4 VGPRs
typedef __attribute__((ext_vector_type(4))) short bf16x4;
typedef __attribute__((ext_vector_type(4))) float f32x4;

// async global->LDS, 16B per lane, dest = ldsbase + lane*16
__device__ __forceinline__ void async_copy16(const void* g, void* l) {
    __builtin_amdgcn_global_load_lds(
        (const __attribute__((address_space(1))) void*)g,
        (__attribute__((address_space(3))) void*)l, 16, 0, 0);
}

__device__ __forceinline__ float gelu_f(float v) {
    float u = 0.7978845608028654f * (v + 0.044715f * v * v * v);
    return 0.5f * v * (1.0f + tanhf(u));
}

__device__ __forceinline__ float block_sum_256(float v, float* sh) {
    #pragma unroll
    for (int off = 32; off > 0; off >>= 1) v += __shfl_down(v, off, 64);
    const int lane = threadIdx.x & 63, w = threadIdx.x >> 6;
    __syncthreads();
    if (lane == 0) sh[w] = v;
    __syncthreads();
    return sh[0] + sh[1] + sh[2] + sh[3];
}

// XCD-aware swizzle: 1D grid of gx*64 blocks (64 row-blocks of 128 rows).
// XCD (id&7) owns row-blocks [xcd*8, xcd*8+8); 8 consecutive slots share a col-block.
__device__ __forceinline__ void swizzle_rc(int id, int& ry, int& cx) {
    ry = (id & 7) * 8 + ((id >> 3) & 7);
    cx = id >> 6;
}

// ---------------------------------------------------------------- gather (bf16 out)
__global__ __launch_bounds__(128) void gather_kernel(
    const int* __restrict__ ids, const float* __restrict__ table,
    const float* __restrict__ pop, __hip_bfloat16* __restrict__ sebf,
    float* __restrict__ debias) {
    const int k = blockIdx.x, t = threadIdx.x;
    const int id = ids[k];
    float4 v = reinterpret_cast<const float4*>(table + (size_t)id * DIM)[t];
    __hip_bfloat16* dst = sebf + (size_t)k * DIM + t * 4;
    dst[0] = __float2bfloat16(v.x);
    dst[1] = __float2bfloat16(v.y);
    dst[2] = __float2bfloat16(v.z);
    dst[3] = __float2bfloat16(v.w);
    if (t == 0) debias[k] = logf(pop[id]);
}

// ---------------------------------------------------------------- masks
__global__ __launch_bounds__(256) void mask_kernel(
    const int* __restrict__ ids, const float* __restrict__ log_mask,
    uint8_t* __restrict__ colmask, uint8_t* __restrict__ padcol) {
    const int bi = blockIdx.x >> 3, seg = blockIdx.x & 7;
    __shared__ int sid[65];
    if (threadIdx.x < 65) sid[threadIdx.x] = ids[bi * 65 + threadIdx.x];
    __syncthreads();
    const int kend = (seg + 1) * (NCOL / 8);
    for (int k = seg * (NCOL / 8) + threadIdx.x; k < kend; k += 256) {
        const int id = ids[k];
        bool mem = false;
        #pragma unroll
        for (int j = 0; j < 65; j++) mem |= (sid[j] == id);
        const int i2 = k / 65, jj = k - i2 * 65;
        const bool pc = (jj < 64) && (log_mask[i2 * 64 + jj] == 0.0f);
        colmask[(size_t)bi * NCOL + k] = (mem || pc) ? 1 : 0;
        if (bi == 0) padcol[k] = pc ? 1 : 0;
    }
}

// ---------------------------------------------------------------- weight transpose+cast
// W[K][N] fp32 -> WT[N][K] bf16; blockIdx.z = layer (stride K*N)
__global__ __launch_bounds__(256) void transpose_bf16_kernel(
    const float* __restrict__ W, __hip_bfloat16* __restrict__ WT, int K, int N) {
    __shared__ float tile[32][33];
    const size_t loff = (size_t)blockIdx.z * K * N;
    const int nt = blockIdx.x * 32, kt = blockIdx.y * 32;
    const int c = threadIdx.x & 31, r = threadIdx.x >> 5;
    #pragma unroll
    for (int p = 0; p < 4; p++)
        tile[p * 8 + r][c] = W[loff + (size_t)(kt + p * 8 + r) * N + nt + c];
    __syncthreads();
    #pragma unroll
    for (int p = 0; p < 4; p++)
        WT[loff + (size_t)(nt + p * 8 + r) * K + kt + c] = __float2bfloat16(tile[c][p * 8 + r]);
}

// ---------------------------------------------------------------- LN kernels
__global__ __launch_bounds__(256) void add_pos_ln_kernel(
    const __hip_bfloat16* __restrict__ sebf, const float* __restrict__ pos,
    float* __restrict__ x, __hip_bfloat16* __restrict__ xb) {
    __shared__ float sh[4];
    const int r = blockIdx.x, b = r >> 6, s = r & 63, t = threadIdx.x;
    const __hip_bfloat16* src = sebf + ((size_t)b * 65 + s) * DIM;
    const float* pp = pos + (size_t)s * DIM;
    float v0 = __bfloat162float(src[t])       + pp[t];
    float v1 = __bfloat162float(src[t + 256]) + pp[t + 256];
    float sum = block_sum_256(v0 + v1, sh);
    float sq  = block_sum_256(v0 * v0 + v1 * v1, sh);
    float mean = sum * (1.0f / 512.0f);
    float var  = sq  * (1.0f / 512.0f) - mean * mean;
    float rs = rsqrtf(var + 1e-5f);
    float o0 = (v0 - mean) * rs, o1 = (v1 - mean) * rs;
    x[(size_t)r * DIM + t]       = o0;
    x[(size_t)r * DIM + t + 256] = o1;
    xb[(size_t)r * DIM + t]       = __float2bfloat16(o0);
    xb[(size_t)r * DIM + t + 256] = __float2bfloat16(o1);
}

__global__ __launch_bounds__(256) void resid_ln_kernel(
    float* __restrict__ x, const __hip_bfloat16* __restrict__ y,
    __hip_bfloat16* __restrict__ xb) {
    __shared__ float sh[4];
    const int r = blockIdx.x, t = threadIdx.x;
    float* xr = x + (size_t)r * DIM;
    const __hip_bfloat16* yr = y + (size_t)r * DIM;
    float v0 = xr[t]       + __bfloat162float(yr[t]);
    float v1 = xr[t + 256] + __bfloat162float(yr[t + 256]);
    float sum = block_sum_256(v0 + v1, sh);
    float sq  = block_sum_256(v0 * v0 + v1 * v1, sh);
    float mean = sum * (1.0f / 512.0f);
    float var  = sq  * (1.0f / 512.0f) - mean * mean;
    float rs = rsqrtf(var + 1e-5f);
    float o0 = (v0 - mean) * rs, o1 = (v1 - mean) * rs;
    xr[t] = o0; xr[t + 256] = o1;
    xb[(size_t)r * DIM + t]       = __float2bfloat16(o0);
    xb[(size_t)r * DIM + t + 256] = __float2bfloat16(o1);
}

// ---------------------------------------------------------------- bf16 MFMA GEMM (B^T)
// C[M,N] = A[M,K] * Bt[N,K]^T, all bf16. Tile 128 x TN, BK=32, 4 waves.
// 1D grid (gx*64) with XCD swizzle; M fixed at 8192.
template<int TN, bool GELU>
__global__ __launch_bounds__(256) void gemm_bt_kernel(
    const __hip_bfloat16* __restrict__ A, const __hip_bfloat16* __restrict__ Bt,
    __hip_bfloat16* __restrict__ C, int N, int K) {
    __shared__ uint16_t As[128 * 32];
    __shared__ uint16_t Bs[TN * 32];
    const int tid = threadIdx.x, w = tid >> 6, lane = tid & 63;
    constexpr int AI = (TN == 128) ? 4 : 2;          // 16-row tiles per wave
    const int wr = (TN == 128) ? (w >> 1) : w;
    const int wc = (TN == 128) ? (w & 1) : 0;
    const int rowbase = wr * (AI * 16);
    int ry, cx;
    swizzle_rc(blockIdx.x, ry, cx);
    const int row0 = ry * 128, col0 = cx * TN;
    const uint16_t* Ag = (const uint16_t*)A;
    const uint16_t* Bg = (const uint16_t*)Bt;
    const int la4 = lane >> 2, lk = (lane & 3) * 8;
    f32x4 acc[AI][4];
    #pragma unroll
    for (int i = 0; i < AI; i++)
        #pragma unroll
        for (int j = 0; j < 4; j++) acc[i][j] = {0.f, 0.f, 0.f, 0.f};

    for (int k0 = 0; k0 < K; k0 += 32) {
        #pragma unroll
        for (int i = 0; i < 2; i++) {
            const int rbase = w * 32 + i * 16;
            async_copy16(Ag + (size_t)(row0 + rbase + la4) * K + k0 + lk, &As[rbase * 32]);
        }
        if (TN == 128) {
            #pragma unroll
            for (int i = 0; i < 2; i++) {
                const int rbase = w * 32 + i * 16;
                async_copy16(Bg + (size_t)(col0 + rbase + la4) * K + k0 + lk, &Bs[rbase * 32]);
            }
        } else {
            const int rbase = w * 16;
            async_copy16(Bg + (size_t)(col0 + rbase + la4) * K + k0 + lk, &Bs[rbase * 32]);
        }
        __syncthreads();
        bf16x8 af[AI], bfr[4];
        #pragma unroll
        for (int i = 0; i < AI; i++)
            af[i] = *(const bf16x8*)&As[(rowbase + i * 16 + (lane & 15)) * 32 + (lane >> 4) * 8];
        #pragma unroll
        for (int j = 0; j < 4; j++)
            bfr[j] = *(const bf16x8*)&Bs[(wc * 64 + j * 16 + (lane & 15)) * 32 + (lane >> 4) * 8];
        #pragma unroll
        for (int i = 0; i < AI; i++)
            #pragma unroll
            for (int j = 0; j < 4; j++)
                acc[i][j] = __builtin_amdgcn_mfma_f32_16x16x32_bf16(af[i], bfr[j], acc[i][j], 0, 0, 0);
        __syncthreads();
    }
    #pragma unroll
    for (int i = 0; i < AI; i++) {
        #pragma unroll
        for (int r = 0; r < 4; r++) {
            const int row = row0 + rowbase + i * 16 + (lane >> 4) * 4 + r;
            #pragma unroll
            for (int j = 0; j < 4; j++) {
                const int col = col0 + wc * 64 + j * 16 + (lane & 15);
                float v = acc[i][j][r];
                if (GELU) v = gelu_f(v);
                C[(size_t)row * N + col] = __float2bfloat16(v);
            }
        }
    }
}

// ---------------------------------------------------------------- MFMA attention (per b,h)
// S = Q@K^T; softmax in C-layout regs; P->LDS; O = P@V with V^T staged in LDS
// so PV B-frags are contiguous bf16x8 reads.
__global__ __launch_bounds__(256) void attn_mfma_kernel(
    const __hip_bfloat16* __restrict__ qkv, const float* __restrict__ log_mask,
    __hip_bfloat16* __restrict__ obuf) {
    constexpr int QS = 72;   // Q/K/P LDS row stride
    constexpr int VS = 72;   // V^T LDS row stride (d-major)
    __shared__ uint16_t Qs[64 * QS];
    __shared__ uint16_t Ks_[64 * QS];
    __shared__ uint16_t Ps[64 * QS];
    __shared__ uint16_t Vt[64 * VS];   // Vt[d][s]
    __shared__ float mask_s[64];
    const int b = blockIdx.x >> 3, h = blockIdx.x & 7;
    const int tid = threadIdx.x, w = tid >> 6, lane = tid & 63;
    const int quad = lane >> 4, l15 = lane & 15;
    const uint16_t* qg = (const uint16_t*)qkv;

    if (tid < 64) mask_s[tid] = log_mask[b * 64 + tid];
    // stage Q,K row-major; V transposed (d-major)
    #pragma unroll
    for (int it = 0; it < 2; it++) {
        const int idx = it * 256 + tid;          // 0..511
        const int s = idx >> 3, c = (idx & 7) * 8;
        const size_t gbase = (size_t)(b * 64 + s) * 1536 + h * 64 + c;
        *(bf16x8*)&Qs[s * QS + c]  = *(const bf16x8*)&qg[gbase];
        *(bf16x8*)&Ks_[s * QS + c] = *(const bf16x8*)&qg[gbase + 512];
        bf16x8 vv = *(const bf16x8*)&qg[gbase + 1024];
        #pragma unroll
        for (int jj = 0; jj < 8; jj++)
            Vt[(c + jj) * VS + s] = (uint16_t)vv[jj];
    }
    __syncthreads();

    // ---- S = Q K^T for rows w*16..w*16+15 (one 16-row strip per wave)
    f32x4 sacc[4];
    #pragma unroll
    for (int j = 0; j < 4; j++) sacc[j] = {0.f, 0.f, 0.f, 0.f};
    #pragma unroll
    for (int k0 = 0; k0 < 2; k0++) {
        bf16x8 aq = *(const bf16x8*)&Qs[(w * 16 + l15) * QS + k0 * 32 + quad * 8];
        #pragma unroll
        for (int j = 0; j < 4; j++) {
            bf16x8 bk = *(const bf16x8*)&Ks_[(j * 16 + l15) * QS + k0 * 32 + quad * 8];
            sacc[j] = __builtin_amdgcn_mfma_f32_16x16x32_bf16(aq, bk, sacc[j], 0, 0, 0);
        }
    }
    // ---- softmax per row (C layout: col = j*16+l15, row = quad*4+r), P -> LDS bf16
    #pragma unroll
    for (int r = 0; r < 4; r++) {
        const int q = w * 16 + quad * 4 + r;
        float vals[4];
        float vmax = -3.0e38f;
        #pragma unroll
        for (int j = 0; j < 4; j++) {
            const int col = j * 16 + l15;
            const bool ok = (col <= q) && (mask_s[col] != 0.0f);
            float v = sacc[j][r] * 0.125f + (ok ? 0.0f : NEG_INF);
            vals[j] = v;
            vmax = fmaxf(vmax, v);
        }
        #pragma unroll
        for (int off = 1; off < 16; off <<= 1) vmax = fmaxf(vmax, __shfl_xor(vmax, off, 64));
        float e[4], s = 0.f;
        #pragma unroll
        for (int j = 0; j < 4; j++) { e[j] = expf(vals[j] - vmax); s += e[j]; }
        #pragma unroll
        for (int off = 1; off < 16; off <<= 1) s += __shfl_xor(s, off, 64);
        const float inv = 1.0f / s;
        #pragma unroll
        for (int j = 0; j < 4; j++) {
            __hip_bfloat16 pb = __float2bfloat16(e[j] * inv);
            Ps[q * QS + j * 16 + l15] = *(uint16_t*)&pb;
        }
    }
    __syncthreads();

    // ---- O = P V : A = P rows, B[n=d][k=s] = Vt[d][s..s+7] contiguous
    f32x4 oacc[4];
    #pragma unroll
    for (int j = 0; j < 4; j++) oacc[j] = {0.f, 0.f, 0.f, 0.f};
    #pragma unroll
    for (int k0 = 0; k0 < 2; k0++) {
        bf16x8 ap = *(const bf16x8*)&Ps[(w * 16 + l15) * QS + k0 * 32 + quad * 8];
        #pragma unroll
        for (int j = 0; j < 4; j++) {
            bf16x8 bv = *(const bf16x8*)&Vt[(j * 16 + l15) * VS + k0 * 32 + quad * 8];
            oacc[j] = __builtin_amdgcn_mfma_f32_16x16x32_bf16(ap, bv, oacc[j], 0, 0, 0);
        }
    }
    #pragma unroll
    for (int r = 0; r < 4; r++) {
        const int q = w * 16 + quad * 4 + r;
        #pragma unroll
        for (int j = 0; j < 4; j++) {
            const int d = j * 16 + l15;
            obuf[(size_t)(b * 64 + q) * 512 + h * 64 + d] = __float2bfloat16(oacc[j][r]);
        }
    }
}

// ---------------------------------------------------------------- fused logits (MFMA + online softmax)
// 1D grid 65*64 with XCD swizzle.
__global__ __launch_bounds__(256) void logits_kernel(
    const __hip_bfloat16* __restrict__ A, const __hip_bfloat16* __restrict__ Bt,
    const float* __restrict__ debias, const uint8_t* __restrict__ colmask,
    const uint8_t* __restrict__ padcol,
    float* __restrict__ partials, float* __restrict__ label_logit) {
    __shared__ uint16_t As[128 * 32];
    __shared__ uint16_t Bs[128 * 32];
    __shared__ float deb_s[128];
    __shared__ uint8_t cm_s[2][128];
    __shared__ uint8_t pc_s[128];
    const int tid = threadIdx.x, w = tid >> 6, lane = tid & 63;
    const int wr = w >> 1, wc = w & 1;
    int ry, cx;
    swizzle_rc(blockIdx.x, ry, cx);
    const int row0 = ry * 128, col0 = cx * 128;
    const uint16_t* Ag = (const uint16_t*)A;
    const uint16_t* Bg = (const uint16_t*)Bt;
    const int la4 = lane >> 2, lk = (lane & 3) * 8;

    if (tid < 128) {
        deb_s[tid] = debias[col0 + tid];
        pc_s[tid]  = padcol[col0 + tid];
        const int bi0 = row0 >> 6;
        cm_s[0][tid] = colmask[(size_t)bi0 * NCOL + col0 + tid];
        cm_s[1][tid] = colmask[(size_t)(bi0 + 1) * NCOL + col0 + tid];
    }

    f32x4 acc[4][4];
    #pragma unroll
    for (int i = 0; i < 4; i++)
        #pragma unroll
        for (int j = 0; j < 4; j++) acc[i][j] = {0.f, 0.f, 0.f, 0.f};

    for (int k0 = 0; k0 < DIM; k0 += 32) {
        #pragma unroll
        for (int i = 0; i < 2; i++) {
            const int rbase = w * 32 + i * 16;
            async_copy16(Ag + (size_t)(row0 + rbase + la4) * DIM + k0 + lk, &As[rbase * 32]);
            async_copy16(Bg + (size_t)(col0 + rbase + la4) * DIM + k0 + lk, &Bs[rbase * 32]);
        }
        __syncthreads();
        bf16x8 af[4], bfr[4];
        #pragma unroll
        for (int i = 0; i < 4; i++) {
            af[i]  = *(const bf16x8*)&As[(wr * 64 + i * 16 + (lane & 15)) * 32 + (lane >> 4) * 8];
            bfr[i] = *(const bf16x8*)&Bs[(wc * 64 + i * 16 + (lane & 15)) * 32 + (lane >> 4) * 8];
        }
        #pragma unroll
        for (int i = 0; i < 4; i++)
            #pragma unroll
            for (int j = 0; j < 4; j++)
                acc[i][j] = __builtin_amdgcn_mfma_f32_16x16x32_bf16(af[i], bfr[j], acc[i][j], 0, 0, 0);
        __syncthreads();
    }

    #pragma unroll
    for (int i = 0; i < 4; i++) {
        #pragma unroll
        for (int r = 0; r < 4; r++) {
            const int lrow = wr * 64 + i * 16 + (lane >> 4) * 4 + r;
            const int row = row0 + lrow;
            const int bi = row >> 6;
            const int label = bi * 65 + (row & 63) + 1;
            float vals[4];
            float vmax = -3.0e38f;
            #pragma unroll
            for (int j = 0; j < 4; j++) {
                const int lcol = wc * 64 + j * 16 + (lane & 15);
                const int col = col0 + lcol;
                float v = acc[i][j][r] - deb_s[lcol];
                const bool is_lab = (col == label);
                const bool masked = is_lab ? (pc_s[lcol] != 0) : (cm_s[lrow >> 6][lcol] != 0);
                if (masked) v = NEG_INF;
                if (is_lab) label_logit[row] = v;
                vals[j] = v;
                vmax = fmaxf(vmax, v);
            }
            #pragma unroll
            for (int off = 1; off < 16; off <<= 1) vmax = fmaxf(vmax, __shfl_xor(vmax, off, 64));
            float s = 0.f;
            #pragma unroll
            for (int j = 0; j < 4; j++) s += expf(vals[j] - vmax);
            #pragma unroll
            for (int off = 1; off < 16; off <<= 1) s += __shfl_xor(s, off, 64);
            if ((lane & 15) == 0) {
                const int strip = (col0 >> 6) + wc;           // 0..129
                const size_t idx = ((size_t)row * 130 + strip) * 2;
                partials[idx]     = vmax;
                partials[idx + 1] = s;
            }
        }
    }
}

// ---------------------------------------------------------------- combine + reduce
__global__ __launch_bounds__(256) void combine_kernel(
    const float* __restrict__ partials, const float* __restrict__ label_logit,
    const float* __restrict__ log_mask, float* __restrict__ bsums) {
    const int row = blockIdx.x * 256 + threadIdx.x;
    const float* p = partials + (size_t)row * 260;
    float M = -3.4e38f;
    for (int t = 0; t < 130; t++) M = fmaxf(M, p[2 * t]);
    float Ls = 0.f;
    for (int t = 0; t < 130; t++) Ls += p[2 * t + 1] * expf(p[2 * t] - M);
    const float lse = M + logf(Ls);
    const float valid = (log_mask[row] != 0.0f) ? 1.0f : 0.0f;
    float a = (lse - label_logit[row]) * valid;
    float c = valid;
    __shared__ float sa[4], sc[4];
    #pragma unroll
    for (int off = 32; off > 0; off >>= 1) {
        a += __shfl_down(a, off, 64);
        c += __shfl_down(c, off, 64);
    }
    const int lane = threadIdx.x & 63, w = threadIdx.x >> 6;
    if (lane == 0) { sa[w] = a; sc[w] = c; }
    __syncthreads();
    if (threadIdx.x == 0) {
        bsums[blockIdx.x * 2 + 0] = sa[0] + sa[1] + sa[2] + sa[3];
        bsums[blockIdx.x * 2 + 1] = sc[0] + sc[1] + sc[2] + sc[3];
    }
}

__global__ __launch_bounds__(64) void finalize_kernel(
    const float* __restrict__ bsums, float* __restrict__ out) {
    const int t = threadIdx.x;
    float a = 0.f, c = 0.f;
    if (t < 32) { a = bsums[2 * t]; c = bsums[2 * t + 1]; }
    #pragma unroll
    for (int off = 32; off > 0; off >>= 1) {
        a += __shfl_down(a, off, 64);
        c += __shfl_down(c, off, 64);
    }
    if (t == 0) out[0] = a / c;
}

// ---------------------------------------------------------------- launch
extern "C" void kernel_launch(void* const* d_in, const int* in_sizes, int n_in,
                              void* d_out, int out_size, void* d_ws, size_t ws_size,
                              hipStream_t stream) {
    const int*   ids    = (const int*)d_in[0];
    const float* lm     = (const float*)d_in[1];
    const float* emb    = (const float*)d_in[2];
    const float* pos    = (const float*)d_in[3];
    const float* qkv_w  = (const float*)d_in[4];
    const float* out_w  = (const float*)d_in[5];
    const float* ffn1_w = (const float*)d_in[6];
    const float* ffn2_w = (const float*)d_in[7];
    const float* pop    = (const float*)d_in[8];
    float* out = (float*)d_out;

    char* p = (char*)d_ws;
    auto alloc = [&](size_t bytes) {
        char* r = p;
        p += (bytes + 255) & ~(size_t)255;
        return r;
    };
    typedef __hip_bfloat16 bf16;
    bf16*    sebf     = (bf16*)alloc((size_t)NCOL * DIM * 2);        // 8.5 MB
    float*   debias   = (float*)alloc((size_t)NCOL * 4);
    uint8_t* padcol   = (uint8_t*)alloc(NCOL);
    uint8_t* colmask  = (uint8_t*)alloc((size_t)BSZ * NCOL);         // 1.06 MB
    float*   x        = (float*)alloc((size_t)NROW * DIM * 4);       // 16.8 MB
    bf16*    xb       = (bf16*)alloc((size_t)NROW * DIM * 2);        // 8.4 MB
    bf16*    big      = (bf16*)alloc((size_t)NROW * 2048 * 2);       // 33.6 MB (qkv / h)
    bf16*    tmp1     = (bf16*)alloc((size_t)NROW * DIM * 2);        // attn out
    bf16*    tmp2     = (bf16*)alloc((size_t)NROW * DIM * 2);        // proj / f2
    float*   partials = (float*)alloc((size_t)NROW * 130 * 2 * 4);   // 8.5 MB
    float*   lab      = (float*)alloc((size_t)NROW * 4);
    float*   bsums    = (float*)alloc(64 * 4);
    bf16*    qkvT     = (bf16*)alloc((size_t)NLAYER * 1536 * 512 * 2);
    bf16*    outT     = (bf16*)alloc((size_t)NLAYER * 512 * 512 * 2);
    bf16*    f1T      = (bf16*)alloc((size_t)NLAYER * 2048 * 512 * 2);
    bf16*    f2T      = (bf16*)alloc((size_t)NLAYER * 512 * 2048 * 2);

    // weight transpose+cast: W[K][N] -> WT[N][K] bf16, all layers per launch
    transpose_bf16_kernel<<<dim3(1536 / 32, 512 / 32, NLAYER), 256, 0, stream>>>(
        qkv_w, qkvT, 512, 1536);
    transpose_bf16_kernel<<<dim3(512 / 32, 512 / 32, NLAYER), 256, 0, stream>>>(
        out_w, outT, 512, 512);
    transpose_bf16_kernel<<<dim3(2048 / 32, 512 / 32, NLAYER), 256, 0, stream>>>(
        ffn1_w, f1T, 512, 2048);
    transpose_bf16_kernel<<<dim3(512 / 32, 2048 / 32, NLAYER), 256, 0, stream>>>(
        ffn2_w, f2T, 2048, 512);

    gather_kernel<<<NCOL, 128, 0, stream>>>(ids, emb, pop, sebf, debias);
    mask_kernel<<<BSZ * 8, 256, 0, stream>>>(ids, lm, colmask, padcol);
    add_pos_ln_kernel<<<NROW, 256, 0, stream>>>(sebf, pos, x, xb);

    for (int l = 0; l < NLAYER; l++) {
        gemm_bt_kernel<128, false><<<(1536 / 128) * 64, 256, 0, stream>>>(
            xb, qkvT + (size_t)l * 1536 * 512, big, 1536, 512);
        attn_mfma_kernel<<<BSZ * HEADS, 256, 0, stream>>>(big, lm, tmp1);
        gemm_bt_kernel<64, false><<<(512 / 64) * 64, 256, 0, stream>>>(
            tmp1, outT + (size_t)l * 512 * 512, tmp2, 512, 512);
        resid_ln_kernel<<<NROW, 256, 0, stream>>>(x, tmp2, xb);
        gemm_bt_kernel<128, true><<<(2048 / 128) * 64, 256, 0, stream>>>(
            xb, f1T + (size_t)l * 2048 * 512, big, 2048, 512);
        gemm_bt_kernel<64, false><<<(512 / 64) * 64, 256, 0, stream>>>(
            big, f2T + (size_t)l * 512 * 2048, tmp2, 512, 2048);
        resid_ln_kernel<<<NROW, 256, 0, stream>>>(x, tmp2, xb);
    }

    logits_kernel<<<65 * 64, 256, 0, stream>>>(
        xb, sebf, debias, colmask, padcol, partials, lab);
    combine_kernel<<<NROW / 256, 256, 0, stream>>>(partials, lab, lm, bsums);
    finalize_kernel<<<1, 64, 0, stream>>>(bsums, out);
}

// Round 5
// 655.225 us; speedup vs baseline: 4.2691x; 1.1523x over previous
//
#include <hip/hip_runtime.h>
#include <hip/hip_bf16.h>
#include <cstdint>
#include <cstddef>

#define NEG_INF -10000.0f

constexpr int BSZ  = 128;
constexpr int SEQ  = 64;     // L
constexpr int DIM  = 512;    // D
constexpr int HEADS = 8;
constexpr int NLAYER = 2;
constexpr int NCOL = BSZ * (SEQ + 1);   // 8320
constexpr int NROW = BSZ * SEQ;         // 8192
constexpr float CMAX = 40.0f;           // analytic upper bound (max logit < 28)

typedef __attribute__((ext_vector_type(8))) short bf16x8;   // 8 bf16 in 4 VGPRs
typedef __attribute__((ext_vector_type(4))) float f32x4;

// async global->LDS, 16B per lane, dest = ldsbase + lane*16
__device__ __forceinline__ void async_copy16(const void* g, void* l) {
    __builtin_amdgcn_global_load_lds(
        (const __attribute__((address_space(1))) void*)g,
        (__attribute__((address_space(3))) void*)l, 16, 0, 0);
}

__device__ __forceinline__ float b2f(uint16_t u) {
    return __builtin_bit_cast(float, (uint32_t)u << 16);
}
__device__ __forceinline__ uint16_t f2b(float f) {
    __hip_bfloat16 h = __float2bfloat16(f);
    return __builtin_bit_cast(uint16_t, h);
}

__device__ __forceinline__ float gelu_f(float v) {
    float u = 0.7978845608028654f * (v + 0.044715f * v * v * v);
    return 0.5f * v * (1.0f + tanhf(u));
}

// XCD-aware swizzle: 1D grid of gx*64 blocks (64 row-blocks of 128 rows).
__device__ __forceinline__ void swizzle_rc(int id, int& ry, int& cx) {
    ry = (id & 7) * 8 + ((id >> 3) & 7);
    cx = id >> 6;
}

// ---------------------------------------------------------------- gather + pos + LN (wave per row)
__global__ __launch_bounds__(256) void gather_posln_kernel(
    const int* __restrict__ ids, const float* __restrict__ table,
    const float* __restrict__ pop, const float* __restrict__ pos,
    __hip_bfloat16* __restrict__ sebf, float* __restrict__ debias,
    __hip_bfloat16* __restrict__ xb) {
    const int w = threadIdx.x >> 6, lane = threadIdx.x & 63;
    const int k = blockIdx.x * 4 + w;              // 0..8319
    const int b = k / 65, s = k - b * 65;
    const int id = ids[k];
    const float* src = table + (size_t)id * DIM + lane * 8;
    float4 u0 = *(const float4*)src;
    float4 u1 = *(const float4*)(src + 4);
    float v[8] = {u0.x, u0.y, u0.z, u0.w, u1.x, u1.y, u1.z, u1.w};
    bf16x8 se;
    #pragma unroll
    for (int j = 0; j < 8; j++) se[j] = (short)f2b(v[j]);
    *(bf16x8*)((uint16_t*)sebf + (size_t)k * DIM + lane * 8) = se;
    if (lane == 0) debias[k] = logf(pop[id]);
    if (s < 64) {
        const float* pp = pos + (size_t)s * DIM + lane * 8;
        float4 p0 = *(const float4*)pp;
        float4 p1 = *(const float4*)(pp + 4);
        float t[8] = {v[0] + p0.x, v[1] + p0.y, v[2] + p0.z, v[3] + p0.w,
                      v[4] + p1.x, v[5] + p1.y, v[6] + p1.z, v[7] + p1.w};
        float sum = 0.f, sq = 0.f;
        #pragma unroll
        for (int j = 0; j < 8; j++) { sum += t[j]; sq += t[j] * t[j]; }
        #pragma unroll
        for (int off = 32; off > 0; off >>= 1) {
            sum += __shfl_xor(sum, off, 64);
            sq  += __shfl_xor(sq,  off, 64);
        }
        const float mean = sum * (1.0f / 512.0f);
        const float var  = sq * (1.0f / 512.0f) - mean * mean;
        const float rs = rsqrtf(var + 1e-5f);
        bf16x8 o;
        #pragma unroll
        for (int j = 0; j < 8; j++) o[j] = (short)f2b((t[j] - mean) * rs);
        *(bf16x8*)((uint16_t*)xb + (size_t)(b * 64 + s) * DIM + lane * 8) = o;
    }
}

// ---------------------------------------------------------------- masks
__global__ __launch_bounds__(256) void mask_kernel(
    const int* __restrict__ ids, const float* __restrict__ log_mask,
    uint8_t* __restrict__ colmask, uint8_t* __restrict__ padcol) {
    const int bi = blockIdx.x >> 3, seg = blockIdx.x & 7;
    __shared__ int sid[65];
    if (threadIdx.x < 65) sid[threadIdx.x] = ids[bi * 65 + threadIdx.x];
    __syncthreads();
    const int kend = (seg + 1) * (NCOL / 8);
    for (int k = seg * (NCOL / 8) + threadIdx.x; k < kend; k += 256) {
        const int id = ids[k];
        bool mem = false;
        #pragma unroll
        for (int j = 0; j < 65; j++) mem |= (sid[j] == id);
        const int i2 = k / 65, jj = k - i2 * 65;
        const bool pc = (jj < 64) && (log_mask[i2 * 64 + jj] == 0.0f);
        colmask[(size_t)bi * NCOL + k] = (mem || pc) ? 1 : 0;
        if (bi == 0) padcol[k] = pc ? 1 : 0;
    }
}

// ---------------------------------------------------------------- weight transpose+cast
__global__ __launch_bounds__(256) void transpose_bf16_kernel(
    const float* __restrict__ W, __hip_bfloat16* __restrict__ WT, int K, int N) {
    __shared__ float tile[32][33];
    const size_t loff = (size_t)blockIdx.z * K * N;
    const int nt = blockIdx.x * 32, kt = blockIdx.y * 32;
    const int c = threadIdx.x & 31, r = threadIdx.x >> 5;
    #pragma unroll
    for (int p = 0; p < 4; p++)
        tile[p * 8 + r][c] = W[loff + (size_t)(kt + p * 8 + r) * N + nt + c];
    __syncthreads();
    #pragma unroll
    for (int p = 0; p < 4; p++)
        WT[loff + (size_t)(nt + p * 8 + r) * K + kt + c] = __float2bfloat16(tile[c][p * 8 + r]);
}

// ---------------------------------------------------------------- residual + LN (wave per row, bf16)
__global__ __launch_bounds__(256) void resid_ln_kernel(
    __hip_bfloat16* __restrict__ xb, const __hip_bfloat16* __restrict__ y) {
    const int w = threadIdx.x >> 6, lane = threadIdx.x & 63;
    const int row = blockIdx.x * 4 + w;
    uint16_t* xp = (uint16_t*)xb + (size_t)row * DIM + lane * 8;
    const uint16_t* yp = (const uint16_t*)y + (size_t)row * DIM + lane * 8;
    bf16x8 xv = *(const bf16x8*)xp;
    bf16x8 yv = *(const bf16x8*)yp;
    float t[8];
    float sum = 0.f, sq = 0.f;
    #pragma unroll
    for (int j = 0; j < 8; j++) {
        t[j] = b2f((uint16_t)xv[j]) + b2f((uint16_t)yv[j]);
        sum += t[j]; sq += t[j] * t[j];
    }
    #pragma unroll
    for (int off = 32; off > 0; off >>= 1) {
        sum += __shfl_xor(sum, off, 64);
        sq  += __shfl_xor(sq,  off, 64);
    }
    const float mean = sum * (1.0f / 512.0f);
    const float var  = sq * (1.0f / 512.0f) - mean * mean;
    const float rs = rsqrtf(var + 1e-5f);
    bf16x8 o;
    #pragma unroll
    for (int j = 0; j < 8; j++) o[j] = (short)f2b((t[j] - mean) * rs);
    *(bf16x8*)xp = o;
}

// ---------------------------------------------------------------- bf16 MFMA GEMM (B^T), BK=64
// C[M,N] = A[M,K] * Bt[N,K]^T. Tile 128 x TN, 4 waves, two 32-wide LDS halves per stage.
template<int TN, bool GELU>
__global__ __launch_bounds__(256) void gemm_bt_kernel(
    const __hip_bfloat16* __restrict__ A, const __hip_bfloat16* __restrict__ Bt,
    __hip_bfloat16* __restrict__ C, int N, int K) {
    __shared__ uint16_t As[2][128][32];
    __shared__ uint16_t Bs[2][TN][32];
    const int tid = threadIdx.x, w = tid >> 6, lane = tid & 63;
    const int quad = lane >> 4, l15 = lane & 15;
    constexpr int AI = (TN == 128) ? 4 : 2;
    const int wr = (TN == 128) ? (w >> 1) : w;
    const int wc = (TN == 128) ? (w & 1) : 0;
    const int rowbase = wr * (AI * 16);
    int ry, cx;
    swizzle_rc(blockIdx.x, ry, cx);
    const int row0 = ry * 128, col0 = cx * TN;
    const uint16_t* Ag = (const uint16_t*)A;
    const uint16_t* Bg = (const uint16_t*)Bt;
    const int sr = lane >> 2, sc = (lane & 3) * 8;
    f32x4 acc[AI][4];
    #pragma unroll
    for (int i = 0; i < AI; i++)
        #pragma unroll
        for (int j = 0; j < 4; j++) acc[i][j] = {0.f, 0.f, 0.f, 0.f};

    for (int k0 = 0; k0 < K; k0 += 64) {
        #pragma unroll
        for (int h = 0; h < 2; h++) {
            #pragma unroll
            for (int i = 0; i < 2; i++) {
                const int rb = w * 32 + i * 16;
                async_copy16(Ag + (size_t)(row0 + rb + sr) * K + k0 + h * 32 + sc, &As[h][rb][0]);
            }
            if (TN == 128) {
                #pragma unroll
                for (int i = 0; i < 2; i++) {
                    const int rb = w * 32 + i * 16;
                    async_copy16(Bg + (size_t)(col0 + rb + sr) * K + k0 + h * 32 + sc, &Bs[h][rb][0]);
                }
            } else {
                const int rb = w * 16;
                async_copy16(Bg + (size_t)(col0 + rb + sr) * K + k0 + h * 32 + sc, &Bs[h][rb][0]);
            }
        }
        __syncthreads();
        #pragma unroll
        for (int h = 0; h < 2; h++) {
            bf16x8 af[AI], bfr[4];
            #pragma unroll
            for (int i = 0; i < AI; i++)
                af[i] = *(const bf16x8*)&As[h][rowbase + i * 16 + l15][quad * 8];
            #pragma unroll
            for (int j = 0; j < 4; j++)
                bfr[j] = *(const bf16x8*)&Bs[h][wc * 64 + j * 16 + l15][quad * 8];
            #pragma unroll
            for (int i = 0; i < AI; i++)
                #pragma unroll
                for (int j = 0; j < 4; j++)
                    acc[i][j] = __builtin_amdgcn_mfma_f32_16x16x32_bf16(af[i], bfr[j], acc[i][j], 0, 0, 0);
        }
        __syncthreads();
    }
    #pragma unroll
    for (int i = 0; i < AI; i++) {
        #pragma unroll
        for (int r = 0; r < 4; r++) {
            const int row = row0 + rowbase + i * 16 + quad * 4 + r;
            #pragma unroll
            for (int j = 0; j < 4; j++) {
                const int col = col0 + wc * 64 + j * 16 + l15;
                float v = acc[i][j][r];
                if (GELU) v = gelu_f(v);
                C[(size_t)row * N + col] = __float2bfloat16(v);
            }
        }
    }
}

// ---------------------------------------------------------------- MFMA attention (per b,h)
__global__ __launch_bounds__(256) void attn_mfma_kernel(
    const __hip_bfloat16* __restrict__ qkv, const float* __restrict__ log_mask,
    __hip_bfloat16* __restrict__ obuf) {
    constexpr int QS = 72;    // Q/K/P LDS row stride (uint16)
    constexpr int VS32 = 36;  // V^T LDS row stride (uint32 pairs)
    __shared__ uint16_t Qs[64 * QS];
    __shared__ uint16_t Ks_[64 * QS];
    __shared__ uint16_t Ps[64 * QS];
    __shared__ uint32_t Vt32[64 * VS32];   // Vt32[d][sp] = (V[2sp][d], V[2sp+1][d])
    __shared__ float mask_s[64];
    const int b = blockIdx.x >> 3, h = blockIdx.x & 7;
    const int tid = threadIdx.x, w = tid >> 6, lane = tid & 63;
    const int quad = lane >> 4, l15 = lane & 15;
    const uint16_t* qg = (const uint16_t*)qkv;

    if (tid < 64) mask_s[tid] = log_mask[b * 64 + tid];
    // stage Q,K row-major
    #pragma unroll
    for (int it = 0; it < 2; it++) {
        const int idx = it * 256 + tid;          // 0..511
        const int s = idx >> 3, c = (idx & 7) * 8;
        const size_t gbase = (size_t)(b * 64 + s) * 1536 + h * 64 + c;
        *(bf16x8*)&Qs[s * QS + c]  = *(const bf16x8*)&qg[gbase];
        *(bf16x8*)&Ks_[s * QS + c] = *(const bf16x8*)&qg[gbase + 512];
    }
    // stage V transposed, two rows packed per 32-bit word
    {
        const int sp = tid >> 3;                 // 0..31
        const int c = (tid & 7) * 8;
        const size_t gbase = (size_t)(b * 64 + sp * 2) * 1536 + 1024 + h * 64 + c;
        bf16x8 v0 = *(const bf16x8*)&qg[gbase];
        bf16x8 v1 = *(const bf16x8*)&qg[gbase + 1536];
        #pragma unroll
        for (int jj = 0; jj < 8; jj++)
            Vt32[(c + jj) * VS32 + sp] =
                (uint32_t)(uint16_t)v0[jj] | ((uint32_t)(uint16_t)v1[jj] << 16);
    }
    __syncthreads();

    // ---- S = Q K^T for rows w*16..w*16+15
    f32x4 sacc[4];
    #pragma unroll
    for (int j = 0; j < 4; j++) sacc[j] = {0.f, 0.f, 0.f, 0.f};
    #pragma unroll
    for (int k0 = 0; k0 < 2; k0++) {
        bf16x8 aq = *(const bf16x8*)&Qs[(w * 16 + l15) * QS + k0 * 32 + quad * 8];
        #pragma unroll
        for (int j = 0; j < 4; j++) {
            bf16x8 bk = *(const bf16x8*)&Ks_[(j * 16 + l15) * QS + k0 * 32 + quad * 8];
            sacc[j] = __builtin_amdgcn_mfma_f32_16x16x32_bf16(aq, bk, sacc[j], 0, 0, 0);
        }
    }
    // ---- softmax per row; P -> LDS bf16
    #pragma unroll
    for (int r = 0; r < 4; r++) {
        const int q = w * 16 + quad * 4 + r;
        float vals[4];
        float vmax = -3.0e38f;
        #pragma unroll
        for (int j = 0; j < 4; j++) {
            const int col = j * 16 + l15;
            const bool ok = (col <= q) && (mask_s[col] != 0.0f);
            float v = sacc[j][r] * 0.125f + (ok ? 0.0f : NEG_INF);
            vals[j] = v;
            vmax = fmaxf(vmax, v);
        }
        #pragma unroll
        for (int off = 1; off < 16; off <<= 1) vmax = fmaxf(vmax, __shfl_xor(vmax, off, 64));
        float e[4], s = 0.f;
        #pragma unroll
        for (int j = 0; j < 4; j++) { e[j] = __expf(vals[j] - vmax); s += e[j]; }
        #pragma unroll
        for (int off = 1; off < 16; off <<= 1) s += __shfl_xor(s, off, 64);
        const float inv = 1.0f / s;
        #pragma unroll
        for (int j = 0; j < 4; j++)
            Ps[q * QS + j * 16 + l15] = f2b(e[j] * inv);
    }
    __syncthreads();

    // ---- O = P V : B-frags contiguous b128 from Vt32
    f32x4 oacc[4];
    #pragma unroll
    for (int j = 0; j < 4; j++) oacc[j] = {0.f, 0.f, 0.f, 0.f};
    #pragma unroll
    for (int k0 = 0; k0 < 2; k0++) {
        bf16x8 ap = *(const bf16x8*)&Ps[(w * 16 + l15) * QS + k0 * 32 + quad * 8];
        #pragma unroll
        for (int j = 0; j < 4; j++) {
            bf16x8 bv = *(const bf16x8*)&Vt32[(j * 16 + l15) * VS32 + k0 * 16 + quad * 4];
            oacc[j] = __builtin_amdgcn_mfma_f32_16x16x32_bf16(ap, bv, oacc[j], 0, 0, 0);
        }
    }
    #pragma unroll
    for (int r = 0; r < 4; r++) {
        const int q = w * 16 + quad * 4 + r;
        #pragma unroll
        for (int j = 0; j < 4; j++) {
            const int d = j * 16 + l15;
            obuf[(size_t)(b * 64 + q) * 512 + h * 64 + d] = __float2bfloat16(oacc[j][r]);
        }
    }
}

// ---------------------------------------------------------------- fused logits (BK=64 + fixed-max softmax)
__global__ __launch_bounds__(256) void logits_kernel(
    const __hip_bfloat16* __restrict__ A, const __hip_bfloat16* __restrict__ Bt,
    const float* __restrict__ debias, const uint8_t* __restrict__ colmask,
    const uint8_t* __restrict__ padcol,
    float* __restrict__ partials, float* __restrict__ label_logit) {
    __shared__ uint16_t As[2][128][32];
    __shared__ uint16_t Bs[2][128][32];
    __shared__ float deb_s[128];
    __shared__ uint8_t cm_s[2][128];
    __shared__ uint8_t pc_s[128];
    const int tid = threadIdx.x, w = tid >> 6, lane = tid & 63;
    const int quad = lane >> 4, l15 = lane & 15;
    const int wr = w >> 1, wc = w & 1;
    int ry, cx;
    swizzle_rc(blockIdx.x, ry, cx);
    const int row0 = ry * 128, col0 = cx * 128;
    const uint16_t* Ag = (const uint16_t*)A;
    const uint16_t* Bg = (const uint16_t*)Bt;
    const int sr = lane >> 2, sc = (lane & 3) * 8;

    if (tid < 128) {
        deb_s[tid] = debias[col0 + tid];
        pc_s[tid]  = padcol[col0 + tid];
        const int bi0 = row0 >> 6;
        cm_s[0][tid] = colmask[(size_t)bi0 * NCOL + col0 + tid];
        cm_s[1][tid] = colmask[(size_t)(bi0 + 1) * NCOL + col0 + tid];
    }

    f32x4 acc[4][4];
    #pragma unroll
    for (int i = 0; i < 4; i++)
        #pragma unroll
        for (int j = 0; j < 4; j++) acc[i][j] = {0.f, 0.f, 0.f, 0.f};

    for (int k0 = 0; k0 < DIM; k0 += 64) {
        #pragma unroll
        for (int h = 0; h < 2; h++) {
            #pragma unroll
            for (int i = 0; i < 2; i++) {
                const int rb = w * 32 + i * 16;
                async_copy16(Ag + (size_t)(row0 + rb + sr) * DIM + k0 + h * 32 + sc, &As[h][rb][0]);
                async_copy16(Bg + (size_t)(col0 + rb + sr) * DIM + k0 + h * 32 + sc, &Bs[h][rb][0]);
            }
        }
        __syncthreads();
        #pragma unroll
        for (int h = 0; h < 2; h++) {
            bf16x8 af[4], bfr[4];
            #pragma unroll
            for (int i = 0; i < 4; i++) {
                af[i]  = *(const bf16x8*)&As[h][wr * 64 + i * 16 + l15][quad * 8];
                bfr[i] = *(const bf16x8*)&Bs[h][wc * 64 + i * 16 + l15][quad * 8];
            }
            #pragma unroll
            for (int i = 0; i < 4; i++)
                #pragma unroll
                for (int j = 0; j < 4; j++)
                    acc[i][j] = __builtin_amdgcn_mfma_f32_16x16x32_bf16(af[i], bfr[j], acc[i][j], 0, 0, 0);
        }
        __syncthreads();
    }

    #pragma unroll
    for (int i = 0; i < 4; i++) {
        #pragma unroll
        for (int r = 0; r < 4; r++) {
            const int lrow = wr * 64 + i * 16 + quad * 4 + r;
            const int row = row0 + lrow;
            const int bi = row >> 6;
            const int label = bi * 65 + (row & 63) + 1;
            float s = 0.f;
            #pragma unroll
            for (int j = 0; j < 4; j++) {
                const int lcol = wc * 64 + j * 16 + l15;
                const int col = col0 + lcol;
                float v = acc[i][j][r] - deb_s[lcol];
                const bool is_lab = (col == label);
                const bool masked = is_lab ? (pc_s[lcol] != 0) : (cm_s[lrow >> 6][lcol] != 0);
                if (masked) v = NEG_INF;
                if (is_lab) label_logit[row] = v;
                s += __expf(v - CMAX);      // masked -> exp(-10040) == 0
            }
            #pragma unroll
            for (int off = 1; off < 16; off <<= 1) s += __shfl_xor(s, off, 64);
            if (l15 == 0) {
                const int strip = (col0 >> 6) + wc;           // 0..129
                partials[(size_t)row * 130 + strip] = s;
            }
        }
    }
}

// ---------------------------------------------------------------- combine + reduce
__global__ __launch_bounds__(256) void combine_kernel(
    const float* __restrict__ partials, const float* __restrict__ label_logit,
    const float* __restrict__ log_mask, float* __restrict__ bsums) {
    const int row = blockIdx.x * 256 + threadIdx.x;
    const float* pr = partials + (size_t)row * 130;
    float Ls = 0.f;
    for (int t = 0; t < 130; t++) Ls += pr[t];
    const float lse = CMAX + logf(Ls);
    const float valid = (log_mask[row] != 0.0f) ? 1.0f : 0.0f;
    float a = (lse - label_logit[row]) * valid;
    float c = valid;
    __shared__ float sa[4], sc_[4];
    #pragma unroll
    for (int off = 32; off > 0; off >>= 1) {
        a += __shfl_down(a, off, 64);
        c += __shfl_down(c, off, 64);
    }
    const int lane = threadIdx.x & 63, w = threadIdx.x >> 6;
    if (lane == 0) { sa[w] = a; sc_[w] = c; }
    __syncthreads();
    if (threadIdx.x == 0) {
        bsums[blockIdx.x * 2 + 0] = sa[0] + sa[1] + sa[2] + sa[3];
        bsums[blockIdx.x * 2 + 1] = sc_[0] + sc_[1] + sc_[2] + sc_[3];
    }
}

__global__ __launch_bounds__(64) void finalize_kernel(
    const float* __restrict__ bsums, float* __restrict__ out) {
    const int t = threadIdx.x;
    float a = 0.f, c = 0.f;
    if (t < 32) { a = bsums[2 * t]; c = bsums[2 * t + 1]; }
    #pragma unroll
    for (int off = 32; off > 0; off >>= 1) {
        a += __shfl_down(a, off, 64);
        c += __shfl_down(c, off, 64);
    }
    if (t == 0) out[0] = a / c;
}

// ---------------------------------------------------------------- launch
extern "C" void kernel_launch(void* const* d_in, const int* in_sizes, int n_in,
                              void* d_out, int out_size, void* d_ws, size_t ws_size,
                              hipStream_t stream) {
    const int*   ids    = (const int*)d_in[0];
    const float* lm     = (const float*)d_in[1];
    const float* emb    = (const float*)d_in[2];
    const float* pos    = (const float*)d_in[3];
    const float* qkv_w  = (const float*)d_in[4];
    const float* out_w  = (const float*)d_in[5];
    const float* ffn1_w = (const float*)d_in[6];
    const float* ffn2_w = (const float*)d_in[7];
    const float* pop    = (const float*)d_in[8];
    float* out = (float*)d_out;

    char* p = (char*)d_ws;
    auto alloc = [&](size_t bytes) {
        char* r = p;
        p += (bytes + 255) & ~(size_t)255;
        return r;
    };
    typedef __hip_bfloat16 bf16;
    bf16*    sebf     = (bf16*)alloc((size_t)NCOL * DIM * 2);        // 8.5 MB
    float*   debias   = (float*)alloc((size_t)NCOL * 4);
    uint8_t* padcol   = (uint8_t*)alloc(NCOL);
    uint8_t* colmask  = (uint8_t*)alloc((size_t)BSZ * NCOL);         // 1.06 MB
    bf16*    xb       = (bf16*)alloc((size_t)NROW * DIM * 2);        // 8.4 MB (residual)
    bf16*    big      = (bf16*)alloc((size_t)NROW * 2048 * 2);       // 33.6 MB (qkv / h)
    bf16*    tmp1     = (bf16*)alloc((size_t)NROW * DIM * 2);        // attn out
    bf16*    tmp2     = (bf16*)alloc((size_t)NROW * DIM * 2);        // proj / f2
    float*   partials = (float*)alloc((size_t)NROW * 130 * 4);       // 4.3 MB
    float*   lab      = (float*)alloc((size_t)NROW * 4);
    float*   bsums    = (float*)alloc(64 * 4);
    bf16*    qkvT     = (bf16*)alloc((size_t)NLAYER * 1536 * 512 * 2);
    bf16*    outT     = (bf16*)alloc((size_t)NLAYER * 512 * 512 * 2);
    bf16*    f1T      = (bf16*)alloc((size_t)NLAYER * 2048 * 512 * 2);
    bf16*    f2T      = (bf16*)alloc((size_t)NLAYER * 512 * 2048 * 2);

    transpose_bf16_kernel<<<dim3(1536 / 32, 512 / 32, NLAYER), 256, 0, stream>>>(
        qkv_w, qkvT, 512, 1536);
    transpose_bf16_kernel<<<dim3(512 / 32, 512 / 32, NLAYER), 256, 0, stream>>>(
        out_w, outT, 512, 512);
    transpose_bf16_kernel<<<dim3(2048 / 32, 512 / 32, NLAYER), 256, 0, stream>>>(
        ffn1_w, f1T, 512, 2048);
    transpose_bf16_kernel<<<dim3(512 / 32, 2048 / 32, NLAYER), 256, 0, stream>>>(
        ffn2_w, f2T, 2048, 512);

    gather_posln_kernel<<<NCOL / 4, 256, 0, stream>>>(ids, emb, pop, pos, sebf, debias, xb);
    mask_kernel<<<BSZ * 8, 256, 0, stream>>>(ids, lm, colmask, padcol);

    for (int l = 0; l < NLAYER; l++) {
        gemm_bt_kernel<128, false><<<(1536 / 128) * 64, 256, 0, stream>>>(
            xb, qkvT + (size_t)l * 1536 * 512, big, 1536, 512);
        attn_mfma_kernel<<<BSZ * HEADS, 256, 0, stream>>>(big, lm, tmp1);
        gemm_bt_kernel<64, false><<<(512 / 64) * 64, 256, 0, stream>>>(
            tmp1, outT + (size_t)l * 512 * 512, tmp2, 512, 512);
        resid_ln_kernel<<<NROW / 4, 256, 0, stream>>>(xb, tmp2);
        gemm_bt_kernel<128, true><<<(2048 / 128) * 64, 256, 0, stream>>>(
            xb, f1T + (size_t)l * 2048 * 512, big, 2048, 512);
        gemm_bt_kernel<64, false><<<(512 / 64) * 64, 256, 0, stream>>>(
            big, f2T + (size_t)l * 512 * 2048, tmp2, 512, 2048);
        resid_ln_kernel<<<NROW / 4, 256, 0, stream>>>(xb, tmp2);
    }

    logits_kernel<<<65 * 64, 256, 0, stream>>>(
        xb, sebf, debias, colmask, padcol, partials, lab);
    combine_kernel<<<NROW / 256, 256, 0, stream>>>(partials, lab, lm, bsums);
    finalize_kernel<<<1, 64, 0, stream>>>(bsums, out);
}